// Round 2
// 780.988 us; speedup vs baseline: 1.0815x; 1.0815x over previous
//
#include <hip/hip_runtime.h>
#include <hip/hip_bf16.h>
#include <math.h>

// ---------------------------------------------------------------------------
// Shapes (fixed by the problem)
// ---------------------------------------------------------------------------
#define B_    4
#define S_    512
#define D_    1024
#define T_    2048          // B*S tokens
#define H_    16
#define HD_   64
#define E_    8
#define HID_  1792
#define D3_   3072
#define GU_   (2 * HID_)    // 3584 interleaved gate/up columns
#define NPART_ 72           // partial chunks per (b,h): sum_{qt<16} (qt/2+1)

typedef unsigned short ushort_t;
typedef __bf16 bf16x8 __attribute__((ext_vector_type(8)));
typedef float  floatx4 __attribute__((ext_vector_type(4)));

__constant__ int kPrefix[16] = {0,1,2,4,6,9,12,16,20,25,30,36,42,49,56,64};

__device__ inline float bf2f(ushort_t u) {
    return __uint_as_float(((unsigned)u) << 16);
}
__device__ inline ushort_t f2bf(float f) {
    __hip_bfloat16 h = __float2bfloat16(f);
    return __builtin_bit_cast(ushort_t, h);
}

// two-word bf16 split: x ~= hi + lo with combined rel error ~2^-17.
// hi = truncated-bf16(x) (exact prefix), lo = rne-bf16(x - hi).
__device__ __forceinline__ void split2(float x, ushort_t& h, ushort_t& l) {
    const unsigned ub = __float_as_uint(x);
    h = (ushort_t)(ub >> 16);
    l = f2bf(x - __uint_as_float(ub & 0xFFFF0000u));
}

// async 16B/lane global->LDS; lds dest wave-uniform base (+lane*16 by HW)
__device__ __forceinline__ void gl2lds16(const ushort_t* g, ushort_t* l) {
    __builtin_amdgcn_global_load_lds(
        (const __attribute__((address_space(1))) void*)g,
        (__attribute__((address_space(3))) void*)l, 16, 0, 0);
}

// ---------------------------------------------------------------------------
// Transpose + fp32->bf16: in (z,R,C) f32 -> out[z*outEstride + (c*mul+add)*R + r]
// ---------------------------------------------------------------------------
__global__ __launch_bounds__(256) void transpose_bf16_kernel(
    const float* __restrict__ in, ushort_t* __restrict__ out,
    int R, int C, int mul, int add, long outEstride)
{
    __shared__ float tile[32][33];
    const int bx = blockIdx.x * 32;           // c
    const int by = blockIdx.y * 32;           // r
    const size_t iofs = (size_t)blockIdx.z * R * C;
    const size_t oofs = (size_t)blockIdx.z * outEstride;
    const int tx = threadIdx.x & 31;
    const int ty = threadIdx.x >> 5;          // 0..7
#pragma unroll
    for (int i = 0; i < 4; i++) {
        int r = by + ty + i * 8;
        tile[ty + i * 8][tx] = in[iofs + (size_t)r * C + bx + tx];
    }
    __syncthreads();
#pragma unroll
    for (int i = 0; i < 4; i++) {
        int c = bx + ty + i * 8;
        out[oofs + (size_t)(c * mul + add) * R + by + tx] = f2bf(tile[tx][ty + i * 8]);
    }
}

// ---------------------------------------------------------------------------
// LayerNorm: x (rows x 1024) f32 -> f32 out and/or bf16 out
// ---------------------------------------------------------------------------
__global__ __launch_bounds__(256) void ln_kernel(
    const float* __restrict__ x, const float* __restrict__ g,
    const float* __restrict__ b, float* __restrict__ outf,
    ushort_t* __restrict__ outb)
{
    const int t = blockIdx.x;
    const int tid = threadIdx.x;
    const int wave = tid >> 6, lane = tid & 63;
    const float4 v = ((const float4*)(x + (size_t)t * D_))[tid];

    float s = v.x + v.y + v.z + v.w;
#pragma unroll
    for (int off = 32; off; off >>= 1) s += __shfl_xor(s, off);
    __shared__ float red1[4];
    __shared__ float red2[4];
    if (lane == 0) red1[wave] = s;
    __syncthreads();
    const float mu = (red1[0] + red1[1] + red1[2] + red1[3]) * (1.0f / D_);

    const float dx = v.x - mu, dy = v.y - mu, dz = v.z - mu, dw = v.w - mu;
    float vs = dx * dx + dy * dy + dz * dz + dw * dw;
#pragma unroll
    for (int off = 32; off; off >>= 1) vs += __shfl_xor(vs, off);
    if (lane == 0) red2[wave] = vs;
    __syncthreads();
    const float var = (red2[0] + red2[1] + red2[2] + red2[3]) * (1.0f / D_);
    const float rs = 1.0f / sqrtf(var + 1e-5f);

    const float4 gg = ((const float4*)g)[tid];
    const float4 bb = ((const float4*)b)[tid];
    float4 o;
    o.x = dx * rs * gg.x + bb.x;
    o.y = dy * rs * gg.y + bb.y;
    o.z = dz * rs * gg.z + bb.z;
    o.w = dw * rs * gg.w + bb.w;
    if (outf) ((float4*)(outf + (size_t)t * D_))[tid] = o;
    if (outb) {
        ushort4 ob;
        ob.x = f2bf(o.x); ob.y = f2bf(o.y); ob.z = f2bf(o.z); ob.w = f2bf(o.w);
        ((ushort4*)(outb + (size_t)t * D_))[tid] = ob;
    }
}

// ---------------------------------------------------------------------------
// f32 SGEMM: tiles TM x 64, BK=16, 256 thr, (TM/16)x4 per thread.
// ---------------------------------------------------------------------------
template<int TM>
__global__ __launch_bounds__(256) void sgemm_kernel(
    const float* __restrict__ A, const float* __restrict__ B,
    const float* __restrict__ res, float* __restrict__ C,
    float* __restrict__ C2, int M, int N, int K)
{
    constexpr int RM  = TM / 16;
    constexpr int TPR = 256 / TM;
    constexpr int KF  = 16 / TPR;
    __shared__ float As[16][TM + 4];
    __shared__ float Bs[16][68];
    const int tid = threadIdx.x;
    const int m0 = blockIdx.y * TM, n0 = blockIdx.x * 64;
    const int tx = tid & 15, ty = tid >> 4;

    float acc[RM][4] = {};

    const int arow = tid / TPR;
    const int akk  = (tid % TPR) * KF;
    const int bk = tid >> 4;
    const int bc = (tid & 15) * 4;

    const float* Ap = A + (size_t)(m0 + arow) * K + akk;
    const float* Bp = B + (size_t)bk * N + n0 + bc;

    for (int k0 = 0; k0 < K; k0 += 16) {
        float av[KF];
#pragma unroll
        for (int f = 0; f < KF / 4; f++) {
            const float4 t = *(const float4*)(Ap + k0 + f * 4);
            av[f * 4 + 0] = t.x; av[f * 4 + 1] = t.y;
            av[f * 4 + 2] = t.z; av[f * 4 + 3] = t.w;
        }
        const float4 bv = *(const float4*)(Bp + (size_t)k0 * N);
        __syncthreads();
#pragma unroll
        for (int i = 0; i < KF; i++) As[akk + i][arow] = av[i];
        *(float4*)&Bs[bk][bc] = bv;
        __syncthreads();
#pragma unroll
        for (int k = 0; k < 16; k++) {
            float a[RM];
#pragma unroll
            for (int f = 0; f < RM / 4; f++) {
                const float4 t = *(const float4*)&As[k][ty * RM + f * 4];
                a[f * 4 + 0] = t.x; a[f * 4 + 1] = t.y;
                a[f * 4 + 2] = t.z; a[f * 4 + 3] = t.w;
            }
            const float4 bb = *(const float4*)&Bs[k][tx * 4];
            const float bj[4] = {bb.x, bb.y, bb.z, bb.w};
#pragma unroll
            for (int i = 0; i < RM; i++)
#pragma unroll
                for (int j = 0; j < 4; j++)
                    acc[i][j] = fmaf(a[i], bj[j], acc[i][j]);
        }
    }

#pragma unroll
    for (int i = 0; i < RM; i++) {
        const int row = m0 + ty * RM + i;
        const size_t base = (size_t)row * N + n0 + tx * 4;
        float4 o;
        o.x = acc[i][0]; o.y = acc[i][1]; o.z = acc[i][2]; o.w = acc[i][3];
        if (res) {
            const float4 r0 = *(const float4*)(res + base);
            o.x += r0.x; o.y += r0.y; o.z += r0.z; o.w += r0.w;
        }
        *(float4*)(C + base) = o;
        if (C2) *(float4*)(C2 + base) = o;
    }
}

// ---------------------------------------------------------------------------
// f32 SGEMM split-K: 128x64 tile, K-slice KS per z; writes Cpart[z].
// ---------------------------------------------------------------------------
__global__ __launch_bounds__(256) void sgemm_splitk_kernel(
    const float* __restrict__ A, const float* __restrict__ B,
    float* __restrict__ Cpart, int M, int N, int K, int KS)
{
    __shared__ float As[16][132];
    __shared__ float Bs[16][68];
    const int tid = threadIdx.x;
    const int m0 = blockIdx.y * 128, n0 = blockIdx.x * 64;
    const int z = blockIdx.z;
    const int kBegin = z * KS;
    const int tx = tid & 15, ty = tid >> 4;

    float acc[8][4] = {};

    const int arow = tid >> 1;           // 0..127
    const int akk  = (tid & 1) * 8;      // 0,8
    const int bk = tid >> 4;             // 0..15
    const int bc = (tid & 15) * 4;       // 0..60

    const float* Ap = A + (size_t)(m0 + arow) * K + kBegin + akk;
    const float* Bp = B + (size_t)(kBegin + bk) * N + n0 + bc;

    for (int k0 = 0; k0 < KS; k0 += 16) {
        float av[8];
#pragma unroll
        for (int f = 0; f < 2; f++) {
            const float4 t = *(const float4*)(Ap + k0 + f * 4);
            av[f * 4 + 0] = t.x; av[f * 4 + 1] = t.y;
            av[f * 4 + 2] = t.z; av[f * 4 + 3] = t.w;
        }
        const float4 bv = *(const float4*)(Bp + (size_t)k0 * N);
        __syncthreads();
#pragma unroll
        for (int i = 0; i < 8; i++) As[akk + i][arow] = av[i];
        *(float4*)&Bs[bk][bc] = bv;
        __syncthreads();
#pragma unroll
        for (int k = 0; k < 16; k++) {
            float a[8];
#pragma unroll
            for (int f = 0; f < 2; f++) {
                const float4 t = *(const float4*)&As[k][ty * 8 + f * 4];
                a[f * 4 + 0] = t.x; a[f * 4 + 1] = t.y;
                a[f * 4 + 2] = t.z; a[f * 4 + 3] = t.w;
            }
            const float4 bb = *(const float4*)&Bs[k][tx * 4];
            const float bj[4] = {bb.x, bb.y, bb.z, bb.w};
#pragma unroll
            for (int i = 0; i < 8; i++)
#pragma unroll
                for (int j = 0; j < 4; j++)
                    acc[i][j] = fmaf(a[i], bj[j], acc[i][j]);
        }
    }

    float* Cz = Cpart + (size_t)z * M * N;
#pragma unroll
    for (int i = 0; i < 8; i++) {
        const int row = m0 + ty * 8 + i;
        const size_t base = (size_t)row * N + n0 + tx * 4;
        float4 o;
        o.x = acc[i][0]; o.y = acc[i][1]; o.z = acc[i][2]; o.w = acc[i][3];
        *(float4*)(Cz + base) = o;
    }
}

// ---------------------------------------------------------------------------
// rope_add: qkv = P0 + P1 (split-K combine), rotate q/k cols, in-place to P0.
// grid (6, T): thread handles 2 consecutive elements.
// ---------------------------------------------------------------------------
__global__ __launch_bounds__(256) void rope_add_kernel(
    float* __restrict__ P0, const float* __restrict__ P1,
    const float* __restrict__ ctab, const float* __restrict__ stab)
{
    const int t = blockIdx.y;
    const int c2 = blockIdx.x * 256 + threadIdx.x;   // 0..1535
    const int col = c2 * 2;
    const size_t idx = (size_t)t * D3_ + col;
    const float2 a0 = *(const float2*)(P0 + idx);
    const float2 a1 = *(const float2*)(P1 + idx);
    float x0 = a0.x + a1.x;
    float x1 = a0.y + a1.y;
    if (col < 2 * D_) {
        const int pair = (col & 63) >> 1;
        const int s = t & (S_ - 1);
        const float c = ctab[s * 32 + pair];
        const float sn = stab[s * 32 + pair];
        const float y0 = x0 * c - x1 * sn;
        const float y1 = x0 * sn + x1 * c;
        x0 = y0; x1 = y1;
    }
    float2 o; o.x = x0; o.y = x1;
    *(float2*)(P0 + idx) = o;
}

// ---------------------------------------------------------------------------
// Routed fused gate+up MoE GEMM: rows gathered from per-expert token lists.
// ---------------------------------------------------------------------------
__global__ __launch_bounds__(256) void gateup_idx_kernel(
    const ushort_t* __restrict__ A, const ushort_t* __restrict__ Bgu,
    const int* __restrict__ cnt, const int* __restrict__ tok,
    ushort_t* __restrict__ Hc)
{
    const int e = blockIdx.z;
    const int cntE = cnt[e];
    const int row0 = blockIdx.y * 128;
    if (row0 >= cntE) return;
    const int col0 = blockIdx.x * 128;
    const ushort_t* Bt = Bgu + (size_t)e * GU_ * D_;
    ushort_t* Hp = Hc + (size_t)e * T_ * HID_;

    __shared__ __align__(16) ushort_t As[128 * 32];
    __shared__ __align__(16) ushort_t Bs[128 * 32];
    const int tid = threadIdx.x, w = tid >> 6, lane = tid & 63;
    const int lr = lane >> 2, lc = (lane & 3) * 8;
    const int wm = (w >> 1) * 64, wn = (w & 1) * 64;
    const int lm = lane & 15, lq = lane >> 4;

    floatx4 acc[4][4] = {};

    int r0c = row0 + w * 16 + lr;  if (r0c > cntE - 1) r0c = cntE - 1;
    int r1c = row0 + 64 + w * 16 + lr; if (r1c > cntE - 1) r1c = cntE - 1;
    const ushort_t* Ap0 = A + (size_t)tok[e * T_ + r0c] * D_ + lc;
    const ushort_t* Ap1 = A + (size_t)tok[e * T_ + r1c] * D_ + lc;
    const ushort_t* Bp = Bt + (size_t)(col0 + w * 16 + lr) * D_ + lc;
    ushort_t* lA = As + w * 512;
    ushort_t* lB = Bs + w * 512;

    for (int k0 = 0; k0 < D_; k0 += 32) {
        __syncthreads();
        gl2lds16(Ap0 + k0, lA);
        gl2lds16(Ap1 + k0, lA + 2048);
        gl2lds16(Bp + k0, lB);
        gl2lds16(Bp + k0 + (size_t)64 * D_, lB + 2048);
        __syncthreads();
        bf16x8 a[4], b[4];
#pragma unroll
        for (int i = 0; i < 4; i++)
            a[i] = *(const bf16x8*)(As + (wm + i * 16 + lm) * 32 + lq * 8);
#pragma unroll
        for (int j = 0; j < 4; j++)
            b[j] = *(const bf16x8*)(Bs + (wn + j * 16 + lm) * 32 + lq * 8);
#pragma unroll
        for (int i = 0; i < 4; i++)
#pragma unroll
            for (int j = 0; j < 4; j++)
                acc[i][j] = __builtin_amdgcn_mfma_f32_16x16x32_bf16(a[i], b[j], acc[i][j], 0, 0, 0);
    }

    // epilogue: adjacent lanes hold (gate, up) for the same hidden unit
#pragma unroll
    for (int i = 0; i < 4; i++)
#pragma unroll
        for (int j = 0; j < 4; j++)
#pragma unroll
            for (int r = 0; r < 4; r++) {
                const float v = acc[i][j][r];
                const float vp = __shfl_xor(v, 1);
                const float g = (lm & 1) ? vp : v;
                const float u = (lm & 1) ? v : vp;
                const float h = g / (1.f + __expf(-g)) * u;
                if (!(lm & 1)) {
                    const int row = row0 + wm + i * 16 + lq * 4 + r;
                    const int col = col0 + wn + j * 16 + lm;    // even
                    Hp[(size_t)row * HID_ + (col >> 1)] = f2bf(h);
                }
            }
}

// ---------------------------------------------------------------------------
// Routed MoE down GEMM, split-K: out[tok[r]] += wt[r] * (Hc[e] @ wd[e]^T).
// grid (8, 16, E*2): z -> (expert, k-slice of HID/2).
// ---------------------------------------------------------------------------
__global__ __launch_bounds__(256) void down_idx_kernel(
    const ushort_t* __restrict__ Hc, const ushort_t* __restrict__ Wd,
    const int* __restrict__ cnt, const int* __restrict__ tok,
    const float* __restrict__ wt, float* __restrict__ out)
{
    const int e = blockIdx.z >> 1;
    const int ks = blockIdx.z & 1;
    const int cntE = cnt[e];
    const int row0 = blockIdx.y * 128;
    if (row0 >= cntE) return;
    const int col0 = blockIdx.x * 128;
    const int kBegin = ks * (HID_ / 2);
    const ushort_t* A = Hc + (size_t)e * T_ * HID_;
    const ushort_t* Bt = Wd + (size_t)e * D_ * HID_;

    __shared__ __align__(16) ushort_t As[128 * 32];
    __shared__ __align__(16) ushort_t Bs[128 * 32];
    const int tid = threadIdx.x, w = tid >> 6, lane = tid & 63;
    const int lr = lane >> 2, lc = (lane & 3) * 8;
    const int wm = (w >> 1) * 64, wn = (w & 1) * 64;
    const int lm = lane & 15, lq = lane >> 4;

    floatx4 acc[4][4] = {};

    const ushort_t* Ap = A + (size_t)(row0 + w * 16 + lr) * HID_ + kBegin + lc;
    const ushort_t* Bp = Bt + (size_t)(col0 + w * 16 + lr) * HID_ + kBegin + lc;
    ushort_t* lA = As + w * 512;
    ushort_t* lB = Bs + w * 512;

    for (int k0 = 0; k0 < HID_ / 2; k0 += 32) {
        __syncthreads();
        gl2lds16(Ap + k0, lA);
        gl2lds16(Ap + k0 + (size_t)64 * HID_, lA + 2048);
        gl2lds16(Bp + k0, lB);
        gl2lds16(Bp + k0 + (size_t)64 * HID_, lB + 2048);
        __syncthreads();
        bf16x8 a[4], b[4];
#pragma unroll
        for (int i = 0; i < 4; i++)
            a[i] = *(const bf16x8*)(As + (wm + i * 16 + lm) * 32 + lq * 8);
#pragma unroll
        for (int j = 0; j < 4; j++)
            b[j] = *(const bf16x8*)(Bs + (wn + j * 16 + lm) * 32 + lq * 8);
#pragma unroll
        for (int i = 0; i < 4; i++)
#pragma unroll
            for (int j = 0; j < 4; j++)
                acc[i][j] = __builtin_amdgcn_mfma_f32_16x16x32_bf16(a[i], b[j], acc[i][j], 0, 0, 0);
    }

#pragma unroll
    for (int i = 0; i < 4; i++)
#pragma unroll
        for (int r = 0; r < 4; r++) {
            const int row = row0 + wm + i * 16 + lq * 4 + r;
            if (row < cntE) {
                const int t = tok[e * T_ + row];
                const float scale = wt[e * T_ + row];
#pragma unroll
                for (int j = 0; j < 4; j++) {
                    const int col = col0 + wn + j * 16 + lm;
                    atomicAdd(&out[(size_t)t * D_ + col], scale * acc[i][j][r]);
                }
            }
        }
}

// ---------------------------------------------------------------------------
// RoPE cos/sin tables (np f32 semantics via f64 pow/cos/sin)
// ---------------------------------------------------------------------------
__global__ __launch_bounds__(256) void rope_table_kernel(
    float* __restrict__ ctab, float* __restrict__ stab)
{
    const int i = blockIdx.x * 256 + threadIdx.x;   // S_*32
    if (i >= S_ * 32) return;
    const int s = i >> 5, p = i & 31;
    const double e = (double)(2 * p) / 64.0;
    const float pf = (float)pow(10000.0, e);
    const float invf = 1.0f / pf;
    const float fr = (float)s * invf;
    ctab[i] = (float)cos((double)fr);
    stab[i] = (float)sin((double)fr);
}

// ---------------------------------------------------------------------------
// Split-K flash attention, pass 1 — two-word bf16 MFMA version.
// Block: (kc, qt, bh), 256 thr = 4 waves. Wave w owns kv/d chunk w*16..+15.
// Every operand X is staged as hi+lo bf16 tiles (X ~= hi+lo, rel err 2^-17);
// each product uses 3 MFMAs: hh + hl + lh (lo*lo dropped, ~2^-34).
// This keeps delta(attn_out) ~ 3e-6, below the MoE-routing flip threshold
// (single-word bf16 at ~3e-3 flipped top-2 expert selections -> absmax 0.47).
// Softmax in f32 (expf), chunk m/l semantics identical to the f32 kernel.
// ---------------------------------------------------------------------------
__global__ __launch_bounds__(256) void attn_part_kernel(
    const float* __restrict__ qkv, float* __restrict__ Opart,
    float* __restrict__ Ml)
{
    const int qt = blockIdx.y;
    const int kc = blockIdx.x;
    if (kc > (qt >> 1)) return;
    const int bh = blockIdx.z;                 // b*16+h
    const int b = bh >> 4, h = bh & 15;
    const int q0 = qt * 32;
    const int c0 = kc * 64;
    const int pidx = bh * NPART_ + kPrefix[qt] + kc;

    // bf16 hi/lo tiles, row stride 72 (pad 8) keeps b128 reads 16B-aligned
    __shared__ __align__(16) ushort_t qsh[32 * 72], qsl[32 * 72];  // Q rows (q, d)
    __shared__ __align__(16) ushort_t ksh[64 * 72], ksl[64 * 72];  // K rows (kv, d)
    __shared__ __align__(16) ushort_t vth[64 * 72], vtl[64 * 72];  // V^T rows (d, kv)
    __shared__ __align__(16) ushort_t psh[32 * 72], psl[32 * 72];  // P rows (q, kv)
    __shared__ __align__(16) float redm[32][4];      // per-wave row max
    __shared__ __align__(16) float redl[32][4];      // per-wave row sum

    const int tid = threadIdx.x, w = tid >> 6, lane = tid & 63;
    const int lm = lane & 15, lq = lane >> 4;

    // ---- stage Q (32x64 f32 -> hi/lo bf16); 8 elements per thread
    {
        const int row = tid >> 3, g = tid & 7;
        const float* src = qkv + (size_t)(b * S_ + q0 + row) * D3_ + h * HD_ + g * 8;
        const float4 v0 = *(const float4*)(src);
        const float4 v1 = *(const float4*)(src + 4);
        ushort4 h0, l0, h1, l1;
        split2(v0.x, h0.x, l0.x); split2(v0.y, h0.y, l0.y);
        split2(v0.z, h0.z, l0.z); split2(v0.w, h0.w, l0.w);
        split2(v1.x, h1.x, l1.x); split2(v1.y, h1.y, l1.y);
        split2(v1.z, h1.z, l1.z); split2(v1.w, h1.w, l1.w);
        *(ushort4*)(qsh + row * 72 + g * 8)     = h0;
        *(ushort4*)(qsh + row * 72 + g * 8 + 4) = h1;
        *(ushort4*)(qsl + row * 72 + g * 8)     = l0;
        *(ushort4*)(qsl + row * 72 + g * 8 + 4) = l1;
    }
    // ---- stage K (64x64 f32 -> hi/lo bf16)
#pragma unroll
    for (int it = 0; it < 2; it++) {
        const int i = tid + it * 256;
        const int row = i >> 3, g = i & 7;
        const float* src = qkv + (size_t)(b * S_ + c0 + row) * D3_ + D_ + h * HD_ + g * 8;
        const float4 v0 = *(const float4*)(src);
        const float4 v1 = *(const float4*)(src + 4);
        ushort4 h0, l0, h1, l1;
        split2(v0.x, h0.x, l0.x); split2(v0.y, h0.y, l0.y);
        split2(v0.z, h0.z, l0.z); split2(v0.w, h0.w, l0.w);
        split2(v1.x, h1.x, l1.x); split2(v1.y, h1.y, l1.y);
        split2(v1.z, h1.z, l1.z); split2(v1.w, h1.w, l1.w);
        *(ushort4*)(ksh + row * 72 + g * 8)     = h0;
        *(ushort4*)(ksh + row * 72 + g * 8 + 4) = h1;
        *(ushort4*)(ksl + row * 72 + g * 8)     = l0;
        *(ushort4*)(ksl + row * 72 + g * 8 + 4) = l1;
    }
    // ---- stage V transposed (V[kv][d] f32 -> vt[d][kv] hi/lo bf16)
#pragma unroll
    for (int it = 0; it < 4; it++) {
        const int i = tid + it * 256;
        const int k = i >> 4, g = i & 15;
        const float4 v = *(const float4*)(qkv + (size_t)(b * S_ + c0 + k) * D3_ + 2 * D_ + h * HD_ + g * 4);
        ushort_t hh, ll;
        split2(v.x, hh, ll); vth[(g * 4 + 0) * 72 + k] = hh; vtl[(g * 4 + 0) * 72 + k] = ll;
        split2(v.y, hh, ll); vth[(g * 4 + 1) * 72 + k] = hh; vtl[(g * 4 + 1) * 72 + k] = ll;
        split2(v.z, hh, ll); vth[(g * 4 + 2) * 72 + k] = hh; vtl[(g * 4 + 2) * 72 + k] = ll;
        split2(v.w, hh, ll); vth[(g * 4 + 3) * 72 + k] = hh; vtl[(g * 4 + 3) * 72 + k] = ll;
    }
    __syncthreads();

    // ---- scores: wave w -> S[32 q][16 kv] chunk; 3 MFMAs per product
    floatx4 acc[2] = {};
#pragma unroll
    for (int k0 = 0; k0 < 64; k0 += 32) {
        const bf16x8 bh16 = *(const bf16x8*)(ksh + (w * 16 + lm) * 72 + k0 + lq * 8);
        const bf16x8 bl16 = *(const bf16x8*)(ksl + (w * 16 + lm) * 72 + k0 + lq * 8);
#pragma unroll
        for (int i = 0; i < 2; i++) {
            const bf16x8 ah = *(const bf16x8*)(qsh + (i * 16 + lm) * 72 + k0 + lq * 8);
            const bf16x8 al = *(const bf16x8*)(qsl + (i * 16 + lm) * 72 + k0 + lq * 8);
            acc[i] = __builtin_amdgcn_mfma_f32_16x16x32_bf16(ah, bh16, acc[i], 0, 0, 0);
            acc[i] = __builtin_amdgcn_mfma_f32_16x16x32_bf16(al, bh16, acc[i], 0, 0, 0);
            acc[i] = __builtin_amdgcn_mfma_f32_16x16x32_bf16(ah, bl16, acc[i], 0, 0, 0);
        }
    }

    // ---- mask + scale, per-row max over this wave's 16 kv (lanes sharing lq)
    float sv[2][4];
    const int kvg = c0 + w * 16 + lm;
#pragma unroll
    for (int i = 0; i < 2; i++)
#pragma unroll
        for (int r = 0; r < 4; r++) {
            const int qg = q0 + i * 16 + lq * 4 + r;
            float v = (kvg <= qg) ? acc[i][r] * 0.125f : -INFINITY;
            sv[i][r] = v;
#pragma unroll
            for (int off = 1; off < 16; off <<= 1) v = fmaxf(v, __shfl_xor(v, off));
            if (lm == 0) redm[i * 16 + lq * 4 + r][w] = v;
        }
    __syncthreads();

    // ---- global (64-kv-chunk) row max, p = exp(s - M) f32, hi/lo split, sums
#pragma unroll
    for (int i = 0; i < 2; i++)
#pragma unroll
        for (int r = 0; r < 4; r++) {
            const int q = i * 16 + lq * 4 + r;
            const float4 m4 = *(const float4*)&redm[q][0];
            const float M = fmaxf(fmaxf(m4.x, m4.y), fmaxf(m4.z, m4.w));
            const float p = expf(sv[i][r] - M);
            ushort_t ph, pl;
            split2(p, ph, pl);
            psh[q * 72 + w * 16 + lm] = ph;
            psl[q * 72 + w * 16 + lm] = pl;
            float sum = p;
#pragma unroll
            for (int off = 1; off < 16; off <<= 1) sum += __shfl_xor(sum, off);
            if (lm == 0) redl[q][w] = sum;
        }
    __syncthreads();

    // ---- write chunk m, l (matches attn_combine expectations)
    if (tid < 32) {
        const float4 m4 = *(const float4*)&redm[tid][0];
        const float4 l4 = *(const float4*)&redl[tid][0];
        Ml[(size_t)pidx * 64 + tid] = fmaxf(fmaxf(m4.x, m4.y), fmaxf(m4.z, m4.w));
        Ml[(size_t)pidx * 64 + 32 + tid] = l4.x + l4.y + l4.z + l4.w;
    }

    // ---- PV: O[32 q][16 d chunk w] = (Ph+Pl) · (Vh+Vl)^T, 3 MFMAs/product
    floatx4 acc2[2] = {};
#pragma unroll
    for (int k0 = 0; k0 < 64; k0 += 32) {
        const bf16x8 bh16 = *(const bf16x8*)(vth + (w * 16 + lm) * 72 + k0 + lq * 8);
        const bf16x8 bl16 = *(const bf16x8*)(vtl + (w * 16 + lm) * 72 + k0 + lq * 8);
#pragma unroll
        for (int i = 0; i < 2; i++) {
            const bf16x8 ah = *(const bf16x8*)(psh + (i * 16 + lm) * 72 + k0 + lq * 8);
            const bf16x8 al = *(const bf16x8*)(psl + (i * 16 + lm) * 72 + k0 + lq * 8);
            acc2[i] = __builtin_amdgcn_mfma_f32_16x16x32_bf16(ah, bh16, acc2[i], 0, 0, 0);
            acc2[i] = __builtin_amdgcn_mfma_f32_16x16x32_bf16(al, bh16, acc2[i], 0, 0, 0);
            acc2[i] = __builtin_amdgcn_mfma_f32_16x16x32_bf16(ah, bl16, acc2[i], 0, 0, 0);
        }
    }
#pragma unroll
    for (int i = 0; i < 2; i++)
#pragma unroll
        for (int r = 0; r < 4; r++)
            Opart[((size_t)pidx * 32 + i * 16 + lq * 4 + r) * 64 + w * 16 + lm] = acc2[i][r];
}

// ---------------------------------------------------------------------------
// Split-K flash attention, pass 2: combine <=8 partials per (bh,qt).
// ---------------------------------------------------------------------------
__global__ __launch_bounds__(256) void attn_combine_kernel(
    const float* __restrict__ Opart, const float* __restrict__ Ml,
    float* __restrict__ out)
{
    const int qt = blockIdx.x, bh = blockIdx.y;
    const int b = bh >> 4, h = bh & 15;
    const int nchunk = (qt >> 1) + 1;
    const int base = bh * NPART_ + kPrefix[qt];
    const int tid = threadIdx.x;
    const int qrow = tid >> 3;            // 0..31
    const int d0 = (tid & 7) * 8;         // 0..56

    float M = -INFINITY;
    for (int c = 0; c < nchunk; c++)
        M = fmaxf(M, Ml[(size_t)(base + c) * 64 + qrow]);

    float L = 0.f;
    float o[8] = {0, 0, 0, 0, 0, 0, 0, 0};
    for (int c = 0; c < nchunk; c++) {
        const float mc = Ml[(size_t)(base + c) * 64 + qrow];
        const float lc = Ml[(size_t)(base + c) * 64 + 32 + qrow];
        const float w = (mc == -INFINITY) ? 0.f : expf(mc - M);
        L = fmaf(lc, w, L);
        const size_t ob = ((size_t)(base + c) * 32 + qrow) * 64 + d0;
        const float4 a0 = *(const float4*)(Opart + ob);
        const float4 a1 = *(const float4*)(Opart + ob + 4);
        o[0] = fmaf(a0.x, w, o[0]); o[1] = fmaf(a0.y, w, o[1]);
        o[2] = fmaf(a0.z, w, o[2]); o[3] = fmaf(a0.w, w, o[3]);
        o[4] = fmaf(a1.x, w, o[4]); o[5] = fmaf(a1.y, w, o[5]);
        o[6] = fmaf(a1.z, w, o[6]); o[7] = fmaf(a1.w, w, o[7]);
    }
    const float inv = 1.f / L;
    const int t = b * S_ + qt * 32 + qrow;
    float4 r0, r1;
    r0.x = o[0] * inv; r0.y = o[1] * inv; r0.z = o[2] * inv; r0.w = o[3] * inv;
    r1.x = o[4] * inv; r1.y = o[5] * inv; r1.z = o[6] * inv; r1.w = o[7] * inv;
    *(float4*)(out + (size_t)t * D_ + h * HD_ + d0) = r0;
    *(float4*)(out + (size_t)t * D_ + h * HD_ + d0 + 4) = r1;
}

// ---------------------------------------------------------------------------
// Gating + routing. bf16-rounded logits, top-2 lowest-index tie-break.
// ---------------------------------------------------------------------------
__global__ __launch_bounds__(64) void gate_kernel(
    const ushort_t* __restrict__ xn2, const float* __restrict__ gate_w,
    int* __restrict__ cnt, int* __restrict__ tok, float* __restrict__ wt,
    float* __restrict__ probs)
{
    const int t = blockIdx.x;
    const int lane = threadIdx.x;
    float acc[8] = {0, 0, 0, 0, 0, 0, 0, 0};
    for (int d = lane; d < D_; d += 64) {
        const float xv = bf2f(xn2[(size_t)t * D_ + d]);
        const float4 g0 = ((const float4*)(gate_w + d * 8))[0];
        const float4 g1 = ((const float4*)(gate_w + d * 8))[1];
        acc[0] = fmaf(xv, bf2f(f2bf(g0.x)), acc[0]);
        acc[1] = fmaf(xv, bf2f(f2bf(g0.y)), acc[1]);
        acc[2] = fmaf(xv, bf2f(f2bf(g0.z)), acc[2]);
        acc[3] = fmaf(xv, bf2f(f2bf(g0.w)), acc[3]);
        acc[4] = fmaf(xv, bf2f(f2bf(g1.x)), acc[4]);
        acc[5] = fmaf(xv, bf2f(f2bf(g1.y)), acc[5]);
        acc[6] = fmaf(xv, bf2f(f2bf(g1.z)), acc[6]);
        acc[7] = fmaf(xv, bf2f(f2bf(g1.w)), acc[7]);
    }
#pragma unroll
    for (int e = 0; e < 8; e++) {
#pragma unroll
        for (int off = 32; off; off >>= 1) acc[e] += __shfl_xor(acc[e], off);
        acc[e] = bf2f(f2bf(acc[e]));   // bf16 result of the bf16 matmul
    }

    if (lane == 0) {
        int i1 = 0;
        for (int e = 1; e < 8; e++) if (acc[e] > acc[i1]) i1 = e;
        int i2 = (i1 == 0) ? 1 : 0;
        for (int e = 0; e < 8; e++) if (e != i1 && acc[e] > acc[i2]) i2 = e;
        const float e2 = expf(acc[i2] - acc[i1]);
        const float w1 = 1.f / (1.f + e2);
        const float w2 = e2 * w1;
        const int p1 = atomicAdd(&cnt[i1], 1);
        tok[i1 * T_ + p1] = t; wt[i1 * T_ + p1] = w1;
        const int p2 = atomicAdd(&cnt[i2], 1);
        tok[i2 * T_ + p2] = t; wt[i2 * T_ + p2] = w2;
        const float mx = acc[i1];
        float se = 0.f, pe[8];
        for (int e = 0; e < 8; e++) { pe[e] = expf(acc[e] - mx); se += pe[e]; }
        const float inv = 1.f / se;
        for (int e = 0; e < 8; e++) probs[t * 8 + e] = pe[e] * inv;
    }
}

__global__ void zero_route_kernel(int* __restrict__ cnt)
{
    if (threadIdx.x < 8) cnt[threadIdx.x] = 0;
}

// ---------------------------------------------------------------------------
// dist = probs.mean(0); lb = E * sum(dist^2); writes out tail.
// ---------------------------------------------------------------------------
__global__ __launch_bounds__(256) void reduce_dist_kernel(
    const float* __restrict__ probs, float* __restrict__ out)
{
    __shared__ float part[256];
    __shared__ float dist8[8];
    const int tid = threadIdx.x;
    const int e = tid & 7, chunk = tid >> 3;   // 32 chunks
    float s = 0.f;
    for (int t = chunk; t < T_; t += 32) s += probs[t * 8 + e];
    part[tid] = s;
    __syncthreads();
    if (tid < 8) {
        float tot = 0.f;
        for (int c = 0; c < 32; c++) tot += part[c * 8 + tid];
        const float dv = tot * (1.0f / T_);
        dist8[tid] = dv;
        out[(size_t)T_ * D_ + 1 + tid] = dv;
    }
    __syncthreads();
    if (tid == 0) {
        float s2 = 0.f;
        for (int k = 0; k < 8; k++) s2 += dist8[k] * dist8[k];
        out[(size_t)T_ * D_] = (float)E_ * s2;
    }
}

// ---------------------------------------------------------------------------
// Launch
// ---------------------------------------------------------------------------
extern "C" void kernel_launch(void* const* d_in, const int* in_sizes, int n_in,
                              void* d_out, int out_size, void* d_ws, size_t ws_size,
                              hipStream_t stream)
{
    const float* x      = (const float*)d_in[0];
    const float* ln1_g  = (const float*)d_in[1];
    const float* ln1_b  = (const float*)d_in[2];
    const float* ln2_g  = (const float*)d_in[3];
    const float* ln2_b  = (const float*)d_in[4];
    const float* w_qkv  = (const float*)d_in[5];
    const float* w_o    = (const float*)d_in[6];
    const float* gate_w = (const float*)d_in[7];
    const float* w_gate = (const float*)d_in[8];
    const float* w_up   = (const float*)d_in[9];
    const float* w_down = (const float*)d_in[10];
    float* out = (float*)d_out;

    char* ws = (char*)d_ws;
    size_t off = 0;
    auto alloc = [&](size_t bytes) { size_t o = off; off += (bytes + 255) & ~(size_t)255; return o; };
    // persistent-through-MoE region
    ushort_t* wguT  = (ushort_t*)(ws + alloc((size_t)E_ * GU_ * D_ * 2));   // 58.7 MB
    ushort_t* wdT   = (ushort_t*)(ws + alloc((size_t)E_ * D_ * HID_ * 2));  // 29.4 MB
    float*    xn    = (float*)   (ws + alloc((size_t)T_ * D_ * 4));
    ushort_t* xn2   = (ushort_t*)(ws + alloc((size_t)T_ * D_ * 2));
    int*      cnt   = (int*)     (ws + alloc(64));
    int*      tok   = (int*)     (ws + alloc((size_t)E_ * T_ * 4));
    float*    wt    = (float*)   (ws + alloc((size_t)E_ * T_ * 4));
    float*    probs = (float*)   (ws + alloc((size_t)T_ * E_ * 4));
    float*    ctab  = (float*)   (ws + alloc((size_t)S_ * 32 * 4));
    float*    stab  = (float*)   (ws + alloc((size_t)S_ * 32 * 4));
    // scratch union (64.1 MB peak, aliased by lifetime):
    //   phase A: qkvP0 [0,25.2) + qkvP1 [25.2,50.4)      (QKV split-K)
    //   phase B: qkv=P0 [0,25.2) + Opart [25.2,63) + Ml [63,64.1)
    //   phase C: attnO [0,8) + x1 [8,16) + Opart/Ml live
    //   phase D: Hc [0,58.7)
    const size_t qkvBytes   = (size_t)T_ * D3_ * 4;
    const size_t opartBytes = (size_t)64 * NPART_ * 32 * 64 * 4;
    const size_t mlBytes    = (size_t)64 * NPART_ * 64 * 4;
    const size_t scratch0 = alloc(qkvBytes + opartBytes + mlBytes);
    float*    qkvP0 = (float*)   (ws + scratch0);
    float*    qkvP1 = (float*)   (ws + scratch0 + qkvBytes);          // also Opart
    float*    Opart = (float*)   (ws + scratch0 + qkvBytes);
    float*    Ml    = (float*)   (ws + scratch0 + qkvBytes + opartBytes);
    float*    attnO = (float*)   (ws + scratch0);                     // alias P0
    float*    x1    = (float*)   (ws + scratch0 + (size_t)T_ * D_ * 4);
    ushort_t* Hc    = (ushort_t*)(ws + scratch0);                     // alias all
    (void)ws_size; (void)in_sizes; (void)n_in; (void)out_size;

    // weight transposes -> bf16 (N x K); gate/up interleaved into wguT
    hipLaunchKernelGGL(transpose_bf16_kernel, dim3(HID_ / 32, D_ / 32, E_), dim3(256), 0, stream,
                       w_gate, wguT, D_, HID_, 2, 0, (long)GU_ * D_);
    hipLaunchKernelGGL(transpose_bf16_kernel, dim3(HID_ / 32, D_ / 32, E_), dim3(256), 0, stream,
                       w_up, wguT, D_, HID_, 2, 1, (long)GU_ * D_);
    hipLaunchKernelGGL(transpose_bf16_kernel, dim3(D_ / 32, HID_ / 32, E_), dim3(256), 0, stream,
                       w_down, wdT, HID_, D_, 1, 0, (long)D_ * HID_);

    // RoPE tables
    hipLaunchKernelGGL(rope_table_kernel, dim3((S_ * 32 + 255) / 256), dim3(256), 0, stream,
                       ctab, stab);

    // LN1 (f32)
    hipLaunchKernelGGL(ln_kernel, dim3(T_), dim3(256), 0, stream,
                       x, ln1_g, ln1_b, xn, (ushort_t*)nullptr);

    // QKV f32 SGEMM, split-K=2: grid (48,16,2) = 1536 blocks
    hipLaunchKernelGGL(sgemm_splitk_kernel, dim3(D3_ / 64, T_ / 128, 2), dim3(256), 0, stream,
                       xn, w_qkv, qkvP0, T_, D3_, D_, D_ / 2);

    // combine K-slices + RoPE (in-place into qkvP0)
    hipLaunchKernelGGL(rope_add_kernel, dim3(6, T_), dim3(256), 0, stream,
                       qkvP0, qkvP1, ctab, stab);

    // attention: split-K partials (two-word bf16 MFMA) + combine
    hipLaunchKernelGGL(attn_part_kernel, dim3(8, 16, 64), dim3(256), 0, stream,
                       qkvP0, Opart, Ml);
    hipLaunchKernelGGL(attn_combine_kernel, dim3(16, 64), dim3(256), 0, stream,
                       Opart, Ml, attnO);

    // W_O SGEMM + residual -> x1 AND out (down_idx accumulates on out)
    hipLaunchKernelGGL((sgemm_kernel<64>), dim3(D_ / 64, T_ / 64), dim3(256), 0, stream,
                       attnO, w_o, x, x1, out, T_, D_, D_);

    // LN2 (bf16)
    hipLaunchKernelGGL(ln_kernel, dim3(T_), dim3(256), 0, stream,
                       x1, ln2_g, ln2_b, (float*)nullptr, xn2);

    // gating + routing + aux outputs
    hipLaunchKernelGGL(zero_route_kernel, dim3(1), dim3(64), 0, stream, cnt);
    hipLaunchKernelGGL(gate_kernel, dim3(T_), dim3(64), 0, stream,
                       xn2, gate_w, cnt, tok, wt, probs);
    hipLaunchKernelGGL(reduce_dist_kernel, dim3(1), dim3(256), 0, stream, probs, out);

    // MoE routed: fused gate+up (+silu), then weighted down (split-K=2)
    hipLaunchKernelGGL(gateup_idx_kernel, dim3(GU_ / 128, T_ / 128, E_), dim3(256), 0, stream,
                       xn2, wguT, cnt, tok, Hc);
    hipLaunchKernelGGL(down_idx_kernel, dim3(D_ / 128, T_ / 128, E_ * 2), dim3(256), 0, stream,
                       Hc, wdT, cnt, tok, wt, out);
}

// Round 3
// 676.146 us; speedup vs baseline: 1.2491x; 1.1551x over previous
//
#include <hip/hip_runtime.h>
#include <hip/hip_bf16.h>
#include <math.h>

// ---------------------------------------------------------------------------
// Shapes (fixed by the problem)
// ---------------------------------------------------------------------------
#define B_    4
#define S_    512
#define D_    1024
#define T_    2048          // B*S tokens
#define H_    16
#define HD_   64
#define E_    8
#define HID_  1792
#define D3_   3072
#define GU_   (2 * HID_)    // 3584 interleaved gate/up columns
#define NPART_ 72           // partial chunks per (b,h): sum_{qt<16} (qt/2+1)

typedef unsigned short ushort_t;
typedef __bf16 bf16x8 __attribute__((ext_vector_type(8)));
typedef float  floatx4 __attribute__((ext_vector_type(4)));

__constant__ int kPrefix[16] = {0,1,2,4,6,9,12,16,20,25,30,36,42,49,56,64};

__device__ inline float bf2f(ushort_t u) {
    return __uint_as_float(((unsigned)u) << 16);
}
__device__ inline ushort_t f2bf(float f) {
    __hip_bfloat16 h = __float2bfloat16(f);
    return __builtin_bit_cast(ushort_t, h);
}

// two-word bf16 split: x ~= hi + lo with combined rel error ~2^-17.
// hi = truncated-bf16(x) (exact prefix), lo = rne-bf16(x - hi).
__device__ __forceinline__ void split2(float x, ushort_t& h, ushort_t& l) {
    const unsigned ub = __float_as_uint(x);
    h = (ushort_t)(ub >> 16);
    l = f2bf(x - __uint_as_float(ub & 0xFFFF0000u));
}

// async 16B/lane global->LDS; lds dest wave-uniform base (+lane*16 by HW)
__device__ __forceinline__ void gl2lds16(const ushort_t* g, ushort_t* l) {
    __builtin_amdgcn_global_load_lds(
        (const __attribute__((address_space(1))) void*)g,
        (__attribute__((address_space(3))) void*)l, 16, 0, 0);
}

// ---------------------------------------------------------------------------
// Transpose + fp32->bf16: in (z,R,C) f32 -> out[z*outEstride + (c*mul+add)*R + r]
// ---------------------------------------------------------------------------
__global__ __launch_bounds__(256) void transpose_bf16_kernel(
    const float* __restrict__ in, ushort_t* __restrict__ out,
    int R, int C, int mul, int add, long outEstride)
{
    __shared__ float tile[32][33];
    const int bx = blockIdx.x * 32;           // c
    const int by = blockIdx.y * 32;           // r
    const size_t iofs = (size_t)blockIdx.z * R * C;
    const size_t oofs = (size_t)blockIdx.z * outEstride;
    const int tx = threadIdx.x & 31;
    const int ty = threadIdx.x >> 5;          // 0..7
#pragma unroll
    for (int i = 0; i < 4; i++) {
        int r = by + ty + i * 8;
        tile[ty + i * 8][tx] = in[iofs + (size_t)r * C + bx + tx];
    }
    __syncthreads();
#pragma unroll
    for (int i = 0; i < 4; i++) {
        int c = bx + ty + i * 8;
        out[oofs + (size_t)(c * mul + add) * R + by + tx] = f2bf(tile[tx][ty + i * 8]);
    }
}

// ---------------------------------------------------------------------------
// Transpose + fp32 -> two-word bf16 planes: in (R,C) f32 -> outh/outl[c*R + r]
// ---------------------------------------------------------------------------
__global__ __launch_bounds__(256) void transpose_split_kernel(
    const float* __restrict__ in, ushort_t* __restrict__ outh,
    ushort_t* __restrict__ outl, int R, int C)
{
    __shared__ float tile[32][33];
    const int bx = blockIdx.x * 32;           // c
    const int by = blockIdx.y * 32;           // r
    const int tx = threadIdx.x & 31;
    const int ty = threadIdx.x >> 5;          // 0..7
#pragma unroll
    for (int i = 0; i < 4; i++) {
        int r = by + ty + i * 8;
        tile[ty + i * 8][tx] = in[(size_t)r * C + bx + tx];
    }
    __syncthreads();
#pragma unroll
    for (int i = 0; i < 4; i++) {
        const int c = bx + ty + i * 8;
        const float v = tile[tx][ty + i * 8];
        ushort_t hh, ll;
        split2(v, hh, ll);
        outh[(size_t)c * R + by + tx] = hh;
        outl[(size_t)c * R + by + tx] = ll;
    }
}

// ---------------------------------------------------------------------------
// LayerNorm: x (rows x 1024) f32 -> optional bf16 out and/or hi/lo bf16 planes
// ---------------------------------------------------------------------------
__global__ __launch_bounds__(256) void ln_kernel(
    const float* __restrict__ x, const float* __restrict__ g,
    const float* __restrict__ b, ushort_t* __restrict__ outb,
    ushort_t* __restrict__ outh, ushort_t* __restrict__ outl)
{
    const int t = blockIdx.x;
    const int tid = threadIdx.x;
    const int wave = tid >> 6, lane = tid & 63;
    const float4 v = ((const float4*)(x + (size_t)t * D_))[tid];

    float s = v.x + v.y + v.z + v.w;
#pragma unroll
    for (int off = 32; off; off >>= 1) s += __shfl_xor(s, off);
    __shared__ float red1[4];
    __shared__ float red2[4];
    if (lane == 0) red1[wave] = s;
    __syncthreads();
    const float mu = (red1[0] + red1[1] + red1[2] + red1[3]) * (1.0f / D_);

    const float dx = v.x - mu, dy = v.y - mu, dz = v.z - mu, dw = v.w - mu;
    float vs = dx * dx + dy * dy + dz * dz + dw * dw;
#pragma unroll
    for (int off = 32; off; off >>= 1) vs += __shfl_xor(vs, off);
    if (lane == 0) red2[wave] = vs;
    __syncthreads();
    const float var = (red2[0] + red2[1] + red2[2] + red2[3]) * (1.0f / D_);
    const float rs = 1.0f / sqrtf(var + 1e-5f);

    const float4 gg = ((const float4*)g)[tid];
    const float4 bb = ((const float4*)b)[tid];
    float4 o;
    o.x = dx * rs * gg.x + bb.x;
    o.y = dy * rs * gg.y + bb.y;
    o.z = dz * rs * gg.z + bb.z;
    o.w = dw * rs * gg.w + bb.w;
    if (outb) {
        ushort4 ob;
        ob.x = f2bf(o.x); ob.y = f2bf(o.y); ob.z = f2bf(o.z); ob.w = f2bf(o.w);
        ((ushort4*)(outb + (size_t)t * D_))[tid] = ob;
    }
    if (outh) {
        ushort4 oh, ol;
        split2(o.x, oh.x, ol.x); split2(o.y, oh.y, ol.y);
        split2(o.z, oh.z, ol.z); split2(o.w, oh.w, ol.w);
        ((ushort4*)(outh + (size_t)t * D_))[tid] = oh;
        ((ushort4*)(outl + (size_t)t * D_))[tid] = ol;
    }
}

// ---------------------------------------------------------------------------
// f32 SGEMM: tiles TM x 64, BK=16, 256 thr, (TM/16)x4 per thread.
// ---------------------------------------------------------------------------
template<int TM>
__global__ __launch_bounds__(256) void sgemm_kernel(
    const float* __restrict__ A, const float* __restrict__ B,
    const float* __restrict__ res, float* __restrict__ C,
    float* __restrict__ C2, int M, int N, int K)
{
    constexpr int RM  = TM / 16;
    constexpr int TPR = 256 / TM;
    constexpr int KF  = 16 / TPR;
    __shared__ float As[16][TM + 4];
    __shared__ float Bs[16][68];
    const int tid = threadIdx.x;
    const int m0 = blockIdx.y * TM, n0 = blockIdx.x * 64;
    const int tx = tid & 15, ty = tid >> 4;

    float acc[RM][4] = {};

    const int arow = tid / TPR;
    const int akk  = (tid % TPR) * KF;
    const int bk = tid >> 4;
    const int bc = (tid & 15) * 4;

    const float* Ap = A + (size_t)(m0 + arow) * K + akk;
    const float* Bp = B + (size_t)bk * N + n0 + bc;

    for (int k0 = 0; k0 < K; k0 += 16) {
        float av[KF];
#pragma unroll
        for (int f = 0; f < KF / 4; f++) {
            const float4 t = *(const float4*)(Ap + k0 + f * 4);
            av[f * 4 + 0] = t.x; av[f * 4 + 1] = t.y;
            av[f * 4 + 2] = t.z; av[f * 4 + 3] = t.w;
        }
        const float4 bv = *(const float4*)(Bp + (size_t)k0 * N);
        __syncthreads();
#pragma unroll
        for (int i = 0; i < KF; i++) As[akk + i][arow] = av[i];
        *(float4*)&Bs[bk][bc] = bv;
        __syncthreads();
#pragma unroll
        for (int k = 0; k < 16; k++) {
            float a[RM];
#pragma unroll
            for (int f = 0; f < RM / 4; f++) {
                const float4 t = *(const float4*)&As[k][ty * RM + f * 4];
                a[f * 4 + 0] = t.x; a[f * 4 + 1] = t.y;
                a[f * 4 + 2] = t.z; a[f * 4 + 3] = t.w;
            }
            const float4 bb = *(const float4*)&Bs[k][tx * 4];
            const float bj[4] = {bb.x, bb.y, bb.z, bb.w};
#pragma unroll
            for (int i = 0; i < RM; i++)
#pragma unroll
                for (int j = 0; j < 4; j++)
                    acc[i][j] = fmaf(a[i], bj[j], acc[i][j]);
        }
    }

#pragma unroll
    for (int i = 0; i < RM; i++) {
        const int row = m0 + ty * RM + i;
        const size_t base = (size_t)row * N + n0 + tx * 4;
        float4 o;
        o.x = acc[i][0]; o.y = acc[i][1]; o.z = acc[i][2]; o.w = acc[i][3];
        if (res) {
            const float4 r0 = *(const float4*)(res + base);
            o.x += r0.x; o.y += r0.y; o.z += r0.z; o.w += r0.w;
        }
        *(float4*)(C + base) = o;
        if (C2) *(float4*)(C2 + base) = o;
    }
}

// ---------------------------------------------------------------------------
// Two-word bf16 MFMA GEMM: C[M x N] = (Ah+Al)[M x K] · (Bh+Bl)[N x K]^T, f32 out.
// 128x128 tile, BK=32, 4 waves, 4x4 16x16x32 MFMAs per wave, 3 per product
// (hh + lh + hl; lo·lo dropped ~2^-34). Same fragment convention as
// gateup_idx_kernel (harness-verified).
// ---------------------------------------------------------------------------
__global__ __launch_bounds__(256) void qkv_mfma_kernel(
    const ushort_t* __restrict__ Ah, const ushort_t* __restrict__ Al,
    const ushort_t* __restrict__ Bh, const ushort_t* __restrict__ Bl,
    float* __restrict__ C)
{
    const int row0 = blockIdx.y * 128, col0 = blockIdx.x * 128;

    __shared__ __align__(16) ushort_t Ash[128 * 32], Asl[128 * 32];
    __shared__ __align__(16) ushort_t Bsh[128 * 32], Bsl[128 * 32];
    const int tid = threadIdx.x, w = tid >> 6, lane = tid & 63;
    const int lr = lane >> 2, lc = (lane & 3) * 8;
    const int wm = (w >> 1) * 64, wn = (w & 1) * 64;
    const int lm = lane & 15, lq = lane >> 4;

    floatx4 acc[4][4] = {};

    const ushort_t* Aph = Ah + (size_t)(row0 + w * 16 + lr) * D_ + lc;
    const ushort_t* Apl = Al + (size_t)(row0 + w * 16 + lr) * D_ + lc;
    const ushort_t* Bph = Bh + (size_t)(col0 + w * 16 + lr) * D_ + lc;
    const ushort_t* Bpl = Bl + (size_t)(col0 + w * 16 + lr) * D_ + lc;
    ushort_t* lAh = Ash + w * 512;
    ushort_t* lAl = Asl + w * 512;
    ushort_t* lBh = Bsh + w * 512;
    ushort_t* lBl = Bsl + w * 512;

    for (int k0 = 0; k0 < D_; k0 += 32) {
        __syncthreads();
        gl2lds16(Aph + k0, lAh);
        gl2lds16(Aph + k0 + (size_t)64 * D_, lAh + 2048);
        gl2lds16(Apl + k0, lAl);
        gl2lds16(Apl + k0 + (size_t)64 * D_, lAl + 2048);
        gl2lds16(Bph + k0, lBh);
        gl2lds16(Bph + k0 + (size_t)64 * D_, lBh + 2048);
        gl2lds16(Bpl + k0, lBl);
        gl2lds16(Bpl + k0 + (size_t)64 * D_, lBl + 2048);
        __syncthreads();
        bf16x8 ah[4], al[4], bh16[4], bl16[4];
#pragma unroll
        for (int i = 0; i < 4; i++) {
            ah[i] = *(const bf16x8*)(Ash + (wm + i * 16 + lm) * 32 + lq * 8);
            al[i] = *(const bf16x8*)(Asl + (wm + i * 16 + lm) * 32 + lq * 8);
        }
#pragma unroll
        for (int j = 0; j < 4; j++) {
            bh16[j] = *(const bf16x8*)(Bsh + (wn + j * 16 + lm) * 32 + lq * 8);
            bl16[j] = *(const bf16x8*)(Bsl + (wn + j * 16 + lm) * 32 + lq * 8);
        }
#pragma unroll
        for (int i = 0; i < 4; i++)
#pragma unroll
            for (int j = 0; j < 4; j++) {
                acc[i][j] = __builtin_amdgcn_mfma_f32_16x16x32_bf16(ah[i], bh16[j], acc[i][j], 0, 0, 0);
                acc[i][j] = __builtin_amdgcn_mfma_f32_16x16x32_bf16(al[i], bh16[j], acc[i][j], 0, 0, 0);
                acc[i][j] = __builtin_amdgcn_mfma_f32_16x16x32_bf16(ah[i], bl16[j], acc[i][j], 0, 0, 0);
            }
    }

#pragma unroll
    for (int i = 0; i < 4; i++)
#pragma unroll
        for (int r = 0; r < 4; r++) {
            const int row = row0 + wm + i * 16 + lq * 4 + r;
#pragma unroll
            for (int j = 0; j < 4; j++) {
                const int col = col0 + wn + j * 16 + lm;
                C[(size_t)row * D3_ + col] = acc[i][j][r];
            }
        }
}

// ---------------------------------------------------------------------------
// rope: rotate q/k cols of qkv in place. grid (4, T): thread handles 2 elems.
// ---------------------------------------------------------------------------
__global__ __launch_bounds__(256) void rope_kernel(
    float* __restrict__ P0,
    const float* __restrict__ ctab, const float* __restrict__ stab)
{
    const int t = blockIdx.y;
    const int c2 = blockIdx.x * 256 + threadIdx.x;   // 0..1023
    const int col = c2 * 2;                           // 0..2046 (q,k only)
    const size_t idx = (size_t)t * D3_ + col;
    const float2 a0 = *(const float2*)(P0 + idx);
    const int pair = (col & 63) >> 1;
    const int s = t & (S_ - 1);
    const float c = ctab[s * 32 + pair];
    const float sn = stab[s * 32 + pair];
    float2 o;
    o.x = a0.x * c - a0.y * sn;
    o.y = a0.x * sn + a0.y * c;
    *(float2*)(P0 + idx) = o;
}

// ---------------------------------------------------------------------------
// Routed fused gate+up MoE GEMM: rows gathered from per-expert token lists.
// ---------------------------------------------------------------------------
__global__ __launch_bounds__(256) void gateup_idx_kernel(
    const ushort_t* __restrict__ A, const ushort_t* __restrict__ Bgu,
    const int* __restrict__ cnt, const int* __restrict__ tok,
    ushort_t* __restrict__ Hc)
{
    const int e = blockIdx.z;
    const int cntE = cnt[e];
    const int row0 = blockIdx.y * 128;
    if (row0 >= cntE) return;
    const int col0 = blockIdx.x * 128;
    const ushort_t* Bt = Bgu + (size_t)e * GU_ * D_;
    ushort_t* Hp = Hc + (size_t)e * T_ * HID_;

    __shared__ __align__(16) ushort_t As[128 * 32];
    __shared__ __align__(16) ushort_t Bs[128 * 32];
    const int tid = threadIdx.x, w = tid >> 6, lane = tid & 63;
    const int lr = lane >> 2, lc = (lane & 3) * 8;
    const int wm = (w >> 1) * 64, wn = (w & 1) * 64;
    const int lm = lane & 15, lq = lane >> 4;

    floatx4 acc[4][4] = {};

    int r0c = row0 + w * 16 + lr;  if (r0c > cntE - 1) r0c = cntE - 1;
    int r1c = row0 + 64 + w * 16 + lr; if (r1c > cntE - 1) r1c = cntE - 1;
    const ushort_t* Ap0 = A + (size_t)tok[e * T_ + r0c] * D_ + lc;
    const ushort_t* Ap1 = A + (size_t)tok[e * T_ + r1c] * D_ + lc;
    const ushort_t* Bp = Bt + (size_t)(col0 + w * 16 + lr) * D_ + lc;
    ushort_t* lA = As + w * 512;
    ushort_t* lB = Bs + w * 512;

    for (int k0 = 0; k0 < D_; k0 += 32) {
        __syncthreads();
        gl2lds16(Ap0 + k0, lA);
        gl2lds16(Ap1 + k0, lA + 2048);
        gl2lds16(Bp + k0, lB);
        gl2lds16(Bp + k0 + (size_t)64 * D_, lB + 2048);
        __syncthreads();
        bf16x8 a[4], b[4];
#pragma unroll
        for (int i = 0; i < 4; i++)
            a[i] = *(const bf16x8*)(As + (wm + i * 16 + lm) * 32 + lq * 8);
#pragma unroll
        for (int j = 0; j < 4; j++)
            b[j] = *(const bf16x8*)(Bs + (wn + j * 16 + lm) * 32 + lq * 8);
#pragma unroll
        for (int i = 0; i < 4; i++)
#pragma unroll
            for (int j = 0; j < 4; j++)
                acc[i][j] = __builtin_amdgcn_mfma_f32_16x16x32_bf16(a[i], b[j], acc[i][j], 0, 0, 0);
    }

    // epilogue: adjacent lanes hold (gate, up) for the same hidden unit
#pragma unroll
    for (int i = 0; i < 4; i++)
#pragma unroll
        for (int j = 0; j < 4; j++)
#pragma unroll
            for (int r = 0; r < 4; r++) {
                const float v = acc[i][j][r];
                const float vp = __shfl_xor(v, 1);
                const float g = (lm & 1) ? vp : v;
                const float u = (lm & 1) ? v : vp;
                const float h = g / (1.f + __expf(-g)) * u;
                if (!(lm & 1)) {
                    const int row = row0 + wm + i * 16 + lq * 4 + r;
                    const int col = col0 + wn + j * 16 + lm;    // even
                    Hp[(size_t)row * HID_ + (col >> 1)] = f2bf(h);
                }
            }
}

// ---------------------------------------------------------------------------
// Routed MoE down GEMM, split-K: out[tok[r]] += wt[r] * (Hc[e] @ wd[e]^T).
// grid (8, 16, E*2): z -> (expert, k-slice of HID/2).
// ---------------------------------------------------------------------------
__global__ __launch_bounds__(256) void down_idx_kernel(
    const ushort_t* __restrict__ Hc, const ushort_t* __restrict__ Wd,
    const int* __restrict__ cnt, const int* __restrict__ tok,
    const float* __restrict__ wt, float* __restrict__ out)
{
    const int e = blockIdx.z >> 1;
    const int ks = blockIdx.z & 1;
    const int cntE = cnt[e];
    const int row0 = blockIdx.y * 128;
    if (row0 >= cntE) return;
    const int col0 = blockIdx.x * 128;
    const int kBegin = ks * (HID_ / 2);
    const ushort_t* A = Hc + (size_t)e * T_ * HID_;
    const ushort_t* Bt = Wd + (size_t)e * D_ * HID_;

    __shared__ __align__(16) ushort_t As[128 * 32];
    __shared__ __align__(16) ushort_t Bs[128 * 32];
    const int tid = threadIdx.x, w = tid >> 6, lane = tid & 63;
    const int lr = lane >> 2, lc = (lane & 3) * 8;
    const int wm = (w >> 1) * 64, wn = (w & 1) * 64;
    const int lm = lane & 15, lq = lane >> 4;

    floatx4 acc[4][4] = {};

    const ushort_t* Ap = A + (size_t)(row0 + w * 16 + lr) * HID_ + kBegin + lc;
    const ushort_t* Bp = Bt + (size_t)(col0 + w * 16 + lr) * HID_ + kBegin + lc;
    ushort_t* lA = As + w * 512;
    ushort_t* lB = Bs + w * 512;

    for (int k0 = 0; k0 < HID_ / 2; k0 += 32) {
        __syncthreads();
        gl2lds16(Ap + k0, lA);
        gl2lds16(Ap + k0 + (size_t)64 * HID_, lA + 2048);
        gl2lds16(Bp + k0, lB);
        gl2lds16(Bp + k0 + (size_t)64 * HID_, lB + 2048);
        __syncthreads();
        bf16x8 a[4], b[4];
#pragma unroll
        for (int i = 0; i < 4; i++)
            a[i] = *(const bf16x8*)(As + (wm + i * 16 + lm) * 32 + lq * 8);
#pragma unroll
        for (int j = 0; j < 4; j++)
            b[j] = *(const bf16x8*)(Bs + (wn + j * 16 + lm) * 32 + lq * 8);
#pragma unroll
        for (int i = 0; i < 4; i++)
#pragma unroll
            for (int j = 0; j < 4; j++)
                acc[i][j] = __builtin_amdgcn_mfma_f32_16x16x32_bf16(a[i], b[j], acc[i][j], 0, 0, 0);
    }

#pragma unroll
    for (int i = 0; i < 4; i++)
#pragma unroll
        for (int r = 0; r < 4; r++) {
            const int row = row0 + wm + i * 16 + lq * 4 + r;
            if (row < cntE) {
                const int t = tok[e * T_ + row];
                const float scale = wt[e * T_ + row];
#pragma unroll
                for (int j = 0; j < 4; j++) {
                    const int col = col0 + wn + j * 16 + lm;
                    atomicAdd(&out[(size_t)t * D_ + col], scale * acc[i][j][r]);
                }
            }
        }
}

// ---------------------------------------------------------------------------
// RoPE cos/sin tables (np f32 semantics via f64 pow/cos/sin)
// ---------------------------------------------------------------------------
__global__ __launch_bounds__(256) void rope_table_kernel(
    float* __restrict__ ctab, float* __restrict__ stab)
{
    const int i = blockIdx.x * 256 + threadIdx.x;   // S_*32
    if (i >= S_ * 32) return;
    const int s = i >> 5, p = i & 31;
    const double e = (double)(2 * p) / 64.0;
    const float pf = (float)pow(10000.0, e);
    const float invf = 1.0f / pf;
    const float fr = (float)s * invf;
    ctab[i] = (float)cos((double)fr);
    stab[i] = (float)sin((double)fr);
}

// ---------------------------------------------------------------------------
// Split-K flash attention, pass 1 — two-word bf16 MFMA version.
// ---------------------------------------------------------------------------
__global__ __launch_bounds__(256) void attn_part_kernel(
    const float* __restrict__ qkv, float* __restrict__ Opart,
    float* __restrict__ Ml)
{
    const int qt = blockIdx.y;
    const int kc = blockIdx.x;
    if (kc > (qt >> 1)) return;
    const int bh = blockIdx.z;                 // b*16+h
    const int b = bh >> 4, h = bh & 15;
    const int q0 = qt * 32;
    const int c0 = kc * 64;
    const int pidx = bh * NPART_ + kPrefix[qt] + kc;

    // bf16 hi/lo tiles, row stride 72 (pad 8) keeps b128 reads 16B-aligned
    __shared__ __align__(16) ushort_t qsh[32 * 72], qsl[32 * 72];  // Q rows (q, d)
    __shared__ __align__(16) ushort_t ksh[64 * 72], ksl[64 * 72];  // K rows (kv, d)
    __shared__ __align__(16) ushort_t vth[64 * 72], vtl[64 * 72];  // V^T rows (d, kv)
    __shared__ __align__(16) ushort_t psh[32 * 72], psl[32 * 72];  // P rows (q, kv)
    __shared__ __align__(16) float redm[32][4];      // per-wave row max
    __shared__ __align__(16) float redl[32][4];      // per-wave row sum

    const int tid = threadIdx.x, w = tid >> 6, lane = tid & 63;
    const int lm = lane & 15, lq = lane >> 4;

    // ---- stage Q (32x64 f32 -> hi/lo bf16); 8 elements per thread
    {
        const int row = tid >> 3, g = tid & 7;
        const float* src = qkv + (size_t)(b * S_ + q0 + row) * D3_ + h * HD_ + g * 8;
        const float4 v0 = *(const float4*)(src);
        const float4 v1 = *(const float4*)(src + 4);
        ushort4 h0, l0, h1, l1;
        split2(v0.x, h0.x, l0.x); split2(v0.y, h0.y, l0.y);
        split2(v0.z, h0.z, l0.z); split2(v0.w, h0.w, l0.w);
        split2(v1.x, h1.x, l1.x); split2(v1.y, h1.y, l1.y);
        split2(v1.z, h1.z, l1.z); split2(v1.w, h1.w, l1.w);
        *(ushort4*)(qsh + row * 72 + g * 8)     = h0;
        *(ushort4*)(qsh + row * 72 + g * 8 + 4) = h1;
        *(ushort4*)(qsl + row * 72 + g * 8)     = l0;
        *(ushort4*)(qsl + row * 72 + g * 8 + 4) = l1;
    }
    // ---- stage K (64x64 f32 -> hi/lo bf16)
#pragma unroll
    for (int it = 0; it < 2; it++) {
        const int i = tid + it * 256;
        const int row = i >> 3, g = i & 7;
        const float* src = qkv + (size_t)(b * S_ + c0 + row) * D3_ + D_ + h * HD_ + g * 8;
        const float4 v0 = *(const float4*)(src);
        const float4 v1 = *(const float4*)(src + 4);
        ushort4 h0, l0, h1, l1;
        split2(v0.x, h0.x, l0.x); split2(v0.y, h0.y, l0.y);
        split2(v0.z, h0.z, l0.z); split2(v0.w, h0.w, l0.w);
        split2(v1.x, h1.x, l1.x); split2(v1.y, h1.y, l1.y);
        split2(v1.z, h1.z, l1.z); split2(v1.w, h1.w, l1.w);
        *(ushort4*)(ksh + row * 72 + g * 8)     = h0;
        *(ushort4*)(ksh + row * 72 + g * 8 + 4) = h1;
        *(ushort4*)(ksl + row * 72 + g * 8)     = l0;
        *(ushort4*)(ksl + row * 72 + g * 8 + 4) = l1;
    }
    // ---- stage V transposed (V[kv][d] f32 -> vt[d][kv] hi/lo bf16)
#pragma unroll
    for (int it = 0; it < 4; it++) {
        const int i = tid + it * 256;
        const int k = i >> 4, g = i & 15;
        const float4 v = *(const float4*)(qkv + (size_t)(b * S_ + c0 + k) * D3_ + 2 * D_ + h * HD_ + g * 4);
        ushort_t hh, ll;
        split2(v.x, hh, ll); vth[(g * 4 + 0) * 72 + k] = hh; vtl[(g * 4 + 0) * 72 + k] = ll;
        split2(v.y, hh, ll); vth[(g * 4 + 1) * 72 + k] = hh; vtl[(g * 4 + 1) * 72 + k] = ll;
        split2(v.z, hh, ll); vth[(g * 4 + 2) * 72 + k] = hh; vtl[(g * 4 + 2) * 72 + k] = ll;
        split2(v.w, hh, ll); vth[(g * 4 + 3) * 72 + k] = hh; vtl[(g * 4 + 3) * 72 + k] = ll;
    }
    __syncthreads();

    // ---- scores: wave w -> S[32 q][16 kv] chunk; 3 MFMAs per product
    floatx4 acc[2] = {};
#pragma unroll
    for (int k0 = 0; k0 < 64; k0 += 32) {
        const bf16x8 bh16 = *(const bf16x8*)(ksh + (w * 16 + lm) * 72 + k0 + lq * 8);
        const bf16x8 bl16 = *(const bf16x8*)(ksl + (w * 16 + lm) * 72 + k0 + lq * 8);
#pragma unroll
        for (int i = 0; i < 2; i++) {
            const bf16x8 ah = *(const bf16x8*)(qsh + (i * 16 + lm) * 72 + k0 + lq * 8);
            const bf16x8 al = *(const bf16x8*)(qsl + (i * 16 + lm) * 72 + k0 + lq * 8);
            acc[i] = __builtin_amdgcn_mfma_f32_16x16x32_bf16(ah, bh16, acc[i], 0, 0, 0);
            acc[i] = __builtin_amdgcn_mfma_f32_16x16x32_bf16(al, bh16, acc[i], 0, 0, 0);
            acc[i] = __builtin_amdgcn_mfma_f32_16x16x32_bf16(ah, bl16, acc[i], 0, 0, 0);
        }
    }

    // ---- mask + scale, per-row max over this wave's 16 kv (lanes sharing lq)
    float sv[2][4];
    const int kvg = c0 + w * 16 + lm;
#pragma unroll
    for (int i = 0; i < 2; i++)
#pragma unroll
        for (int r = 0; r < 4; r++) {
            const int qg = q0 + i * 16 + lq * 4 + r;
            float v = (kvg <= qg) ? acc[i][r] * 0.125f : -INFINITY;
            sv[i][r] = v;
#pragma unroll
            for (int off = 1; off < 16; off <<= 1) v = fmaxf(v, __shfl_xor(v, off));
            if (lm == 0) redm[i * 16 + lq * 4 + r][w] = v;
        }
    __syncthreads();

    // ---- global (64-kv-chunk) row max, p = exp(s - M) f32, hi/lo split, sums
#pragma unroll
    for (int i = 0; i < 2; i++)
#pragma unroll
        for (int r = 0; r < 4; r++) {
            const int q = i * 16 + lq * 4 + r;
            const float4 m4 = *(const float4*)&redm[q][0];
            const float M = fmaxf(fmaxf(m4.x, m4.y), fmaxf(m4.z, m4.w));
            const float p = expf(sv[i][r] - M);
            ushort_t ph, pl;
            split2(p, ph, pl);
            psh[q * 72 + w * 16 + lm] = ph;
            psl[q * 72 + w * 16 + lm] = pl;
            float sum = p;
#pragma unroll
            for (int off = 1; off < 16; off <<= 1) sum += __shfl_xor(sum, off);
            if (lm == 0) redl[q][w] = sum;
        }
    __syncthreads();

    // ---- write chunk m, l (matches attn_combine expectations)
    if (tid < 32) {
        const float4 m4 = *(const float4*)&redm[tid][0];
        const float4 l4 = *(const float4*)&redl[tid][0];
        Ml[(size_t)pidx * 64 + tid] = fmaxf(fmaxf(m4.x, m4.y), fmaxf(m4.z, m4.w));
        Ml[(size_t)pidx * 64 + 32 + tid] = l4.x + l4.y + l4.z + l4.w;
    }

    // ---- PV: O[32 q][16 d chunk w] = (Ph+Pl) · (Vh+Vl)^T, 3 MFMAs/product
    floatx4 acc2[2] = {};
#pragma unroll
    for (int k0 = 0; k0 < 64; k0 += 32) {
        const bf16x8 bh16 = *(const bf16x8*)(vth + (w * 16 + lm) * 72 + k0 + lq * 8);
        const bf16x8 bl16 = *(const bf16x8*)(vtl + (w * 16 + lm) * 72 + k0 + lq * 8);
#pragma unroll
        for (int i = 0; i < 2; i++) {
            const bf16x8 ah = *(const bf16x8*)(psh + (i * 16 + lm) * 72 + k0 + lq * 8);
            const bf16x8 al = *(const bf16x8*)(psl + (i * 16 + lm) * 72 + k0 + lq * 8);
            acc2[i] = __builtin_amdgcn_mfma_f32_16x16x32_bf16(ah, bh16, acc2[i], 0, 0, 0);
            acc2[i] = __builtin_amdgcn_mfma_f32_16x16x32_bf16(al, bh16, acc2[i], 0, 0, 0);
            acc2[i] = __builtin_amdgcn_mfma_f32_16x16x32_bf16(ah, bl16, acc2[i], 0, 0, 0);
        }
    }
#pragma unroll
    for (int i = 0; i < 2; i++)
#pragma unroll
        for (int r = 0; r < 4; r++)
            Opart[((size_t)pidx * 32 + i * 16 + lq * 4 + r) * 64 + w * 16 + lm] = acc2[i][r];
}

// ---------------------------------------------------------------------------
// Split-K flash attention, pass 2: combine <=8 partials per (bh,qt).
// ---------------------------------------------------------------------------
__global__ __launch_bounds__(256) void attn_combine_kernel(
    const float* __restrict__ Opart, const float* __restrict__ Ml,
    float* __restrict__ out)
{
    const int qt = blockIdx.x, bh = blockIdx.y;
    const int b = bh >> 4, h = bh & 15;
    const int nchunk = (qt >> 1) + 1;
    const int base = bh * NPART_ + kPrefix[qt];
    const int tid = threadIdx.x;
    const int qrow = tid >> 3;            // 0..31
    const int d0 = (tid & 7) * 8;         // 0..56

    float M = -INFINITY;
    for (int c = 0; c < nchunk; c++)
        M = fmaxf(M, Ml[(size_t)(base + c) * 64 + qrow]);

    float L = 0.f;
    float o[8] = {0, 0, 0, 0, 0, 0, 0, 0};
    for (int c = 0; c < nchunk; c++) {
        const float mc = Ml[(size_t)(base + c) * 64 + qrow];
        const float lc = Ml[(size_t)(base + c) * 64 + 32 + qrow];
        const float w = (mc == -INFINITY) ? 0.f : expf(mc - M);
        L = fmaf(lc, w, L);
        const size_t ob = ((size_t)(base + c) * 32 + qrow) * 64 + d0;
        const float4 a0 = *(const float4*)(Opart + ob);
        const float4 a1 = *(const float4*)(Opart + ob + 4);
        o[0] = fmaf(a0.x, w, o[0]); o[1] = fmaf(a0.y, w, o[1]);
        o[2] = fmaf(a0.z, w, o[2]); o[3] = fmaf(a0.w, w, o[3]);
        o[4] = fmaf(a1.x, w, o[4]); o[5] = fmaf(a1.y, w, o[5]);
        o[6] = fmaf(a1.z, w, o[6]); o[7] = fmaf(a1.w, w, o[7]);
    }
    const float inv = 1.f / L;
    const int t = b * S_ + qt * 32 + qrow;
    float4 r0, r1;
    r0.x = o[0] * inv; r0.y = o[1] * inv; r0.z = o[2] * inv; r0.w = o[3] * inv;
    r1.x = o[4] * inv; r1.y = o[5] * inv; r1.z = o[6] * inv; r1.w = o[7] * inv;
    *(float4*)(out + (size_t)t * D_ + h * HD_ + d0) = r0;
    *(float4*)(out + (size_t)t * D_ + h * HD_ + d0 + 4) = r1;
}

// ---------------------------------------------------------------------------
// Gating + routing. bf16-rounded logits, top-2 lowest-index tie-break.
// ---------------------------------------------------------------------------
__global__ __launch_bounds__(64) void gate_kernel(
    const ushort_t* __restrict__ xn2, const float* __restrict__ gate_w,
    int* __restrict__ cnt, int* __restrict__ tok, float* __restrict__ wt,
    float* __restrict__ probs)
{
    const int t = blockIdx.x;
    const int lane = threadIdx.x;
    float acc[8] = {0, 0, 0, 0, 0, 0, 0, 0};
    for (int d = lane; d < D_; d += 64) {
        const float xv = bf2f(xn2[(size_t)t * D_ + d]);
        const float4 g0 = ((const float4*)(gate_w + d * 8))[0];
        const float4 g1 = ((const float4*)(gate_w + d * 8))[1];
        acc[0] = fmaf(xv, bf2f(f2bf(g0.x)), acc[0]);
        acc[1] = fmaf(xv, bf2f(f2bf(g0.y)), acc[1]);
        acc[2] = fmaf(xv, bf2f(f2bf(g0.z)), acc[2]);
        acc[3] = fmaf(xv, bf2f(f2bf(g0.w)), acc[3]);
        acc[4] = fmaf(xv, bf2f(f2bf(g1.x)), acc[4]);
        acc[5] = fmaf(xv, bf2f(f2bf(g1.y)), acc[5]);
        acc[6] = fmaf(xv, bf2f(f2bf(g1.z)), acc[6]);
        acc[7] = fmaf(xv, bf2f(f2bf(g1.w)), acc[7]);
    }
#pragma unroll
    for (int e = 0; e < 8; e++) {
#pragma unroll
        for (int off = 32; off; off >>= 1) acc[e] += __shfl_xor(acc[e], off);
        acc[e] = bf2f(f2bf(acc[e]));   // bf16 result of the bf16 matmul
    }

    if (lane == 0) {
        int i1 = 0;
        for (int e = 1; e < 8; e++) if (acc[e] > acc[i1]) i1 = e;
        int i2 = (i1 == 0) ? 1 : 0;
        for (int e = 0; e < 8; e++) if (e != i1 && acc[e] > acc[i2]) i2 = e;
        const float e2 = expf(acc[i2] - acc[i1]);
        const float w1 = 1.f / (1.f + e2);
        const float w2 = e2 * w1;
        const int p1 = atomicAdd(&cnt[i1], 1);
        tok[i1 * T_ + p1] = t; wt[i1 * T_ + p1] = w1;
        const int p2 = atomicAdd(&cnt[i2], 1);
        tok[i2 * T_ + p2] = t; wt[i2 * T_ + p2] = w2;
        const float mx = acc[i1];
        float se = 0.f, pe[8];
        for (int e = 0; e < 8; e++) { pe[e] = expf(acc[e] - mx); se += pe[e]; }
        const float inv = 1.f / se;
        for (int e = 0; e < 8; e++) probs[t * 8 + e] = pe[e] * inv;
    }
}

__global__ void zero_route_kernel(int* __restrict__ cnt)
{
    if (threadIdx.x < 8) cnt[threadIdx.x] = 0;
}

// ---------------------------------------------------------------------------
// dist = probs.mean(0); lb = E * sum(dist^2); writes out tail.
// ---------------------------------------------------------------------------
__global__ __launch_bounds__(256) void reduce_dist_kernel(
    const float* __restrict__ probs, float* __restrict__ out)
{
    __shared__ float part[256];
    __shared__ float dist8[8];
    const int tid = threadIdx.x;
    const int e = tid & 7, chunk = tid >> 3;   // 32 chunks
    float s = 0.f;
    for (int t = chunk; t < T_; t += 32) s += probs[t * 8 + e];
    part[tid] = s;
    __syncthreads();
    if (tid < 8) {
        float tot = 0.f;
        for (int c = 0; c < 32; c++) tot += part[c * 8 + tid];
        const float dv = tot * (1.0f / T_);
        dist8[tid] = dv;
        out[(size_t)T_ * D_ + 1 + tid] = dv;
    }
    __syncthreads();
    if (tid == 0) {
        float s2 = 0.f;
        for (int k = 0; k < 8; k++) s2 += dist8[k] * dist8[k];
        out[(size_t)T_ * D_] = (float)E_ * s2;
    }
}

// ---------------------------------------------------------------------------
// Launch
// ---------------------------------------------------------------------------
extern "C" void kernel_launch(void* const* d_in, const int* in_sizes, int n_in,
                              void* d_out, int out_size, void* d_ws, size_t ws_size,
                              hipStream_t stream)
{
    const float* x      = (const float*)d_in[0];
    const float* ln1_g  = (const float*)d_in[1];
    const float* ln1_b  = (const float*)d_in[2];
    const float* ln2_g  = (const float*)d_in[3];
    const float* ln2_b  = (const float*)d_in[4];
    const float* w_qkv  = (const float*)d_in[5];
    const float* w_o    = (const float*)d_in[6];
    const float* gate_w = (const float*)d_in[7];
    const float* w_gate = (const float*)d_in[8];
    const float* w_up   = (const float*)d_in[9];
    const float* w_down = (const float*)d_in[10];
    float* out = (float*)d_out;

    char* ws = (char*)d_ws;
    size_t off = 0;
    auto alloc = [&](size_t bytes) { size_t o = off; off += (bytes + 255) & ~(size_t)255; return o; };
    // persistent-through-MoE region
    ushort_t* wguT  = (ushort_t*)(ws + alloc((size_t)E_ * GU_ * D_ * 2));   // 58.7 MB
    ushort_t* wdT   = (ushort_t*)(ws + alloc((size_t)E_ * D_ * HID_ * 2));  // 29.4 MB
    ushort_t* xnh   = (ushort_t*)(ws + alloc((size_t)T_ * D_ * 4));         // hi+lo planes
    ushort_t* xnl   = xnh + (size_t)T_ * D_;
    ushort_t* xn2   = (ushort_t*)(ws + alloc((size_t)T_ * D_ * 2));
    int*      cnt   = (int*)     (ws + alloc(64));
    int*      tok   = (int*)     (ws + alloc((size_t)E_ * T_ * 4));
    float*    wt    = (float*)   (ws + alloc((size_t)E_ * T_ * 4));
    float*    probs = (float*)   (ws + alloc((size_t)T_ * E_ * 4));
    float*    ctab  = (float*)   (ws + alloc((size_t)S_ * 32 * 4));
    float*    stab  = (float*)   (ws + alloc((size_t)S_ * 32 * 4));
    // scratch union (64.1 MB peak, aliased by lifetime):
    //   phase A: qkvP0 [0,25.2) + wqkvT hi/lo [25.2,37.8)   (QKV MFMA GEMM)
    //   phase B: qkv=P0 [0,25.2) + Opart [25.2,63) + Ml [63,64.1)
    //   phase C: attnO [0,8) + x1 [8,16) + Opart/Ml live
    //   phase D: Hc [0,58.7)
    const size_t qkvBytes   = (size_t)T_ * D3_ * 4;
    const size_t opartBytes = (size_t)64 * NPART_ * 32 * 64 * 4;
    const size_t mlBytes    = (size_t)64 * NPART_ * 64 * 4;
    const size_t scratch0 = alloc(qkvBytes + opartBytes + mlBytes);
    float*    qkvP0 = (float*)   (ws + scratch0);
    ushort_t* wqkvTh= (ushort_t*)(ws + scratch0 + qkvBytes);          // dead before Opart
    ushort_t* wqkvTl= wqkvTh + (size_t)D3_ * D_;
    float*    Opart = (float*)   (ws + scratch0 + qkvBytes);
    float*    Ml    = (float*)   (ws + scratch0 + qkvBytes + opartBytes);
    float*    attnO = (float*)   (ws + scratch0);                     // alias P0
    float*    x1    = (float*)   (ws + scratch0 + (size_t)T_ * D_ * 4);
    ushort_t* Hc    = (ushort_t*)(ws + scratch0);                     // alias all
    (void)ws_size; (void)in_sizes; (void)n_in; (void)out_size;

    // weight transposes -> bf16 (N x K); gate/up interleaved into wguT
    hipLaunchKernelGGL(transpose_bf16_kernel, dim3(HID_ / 32, D_ / 32, E_), dim3(256), 0, stream,
                       w_gate, wguT, D_, HID_, 2, 0, (long)GU_ * D_);
    hipLaunchKernelGGL(transpose_bf16_kernel, dim3(HID_ / 32, D_ / 32, E_), dim3(256), 0, stream,
                       w_up, wguT, D_, HID_, 2, 1, (long)GU_ * D_);
    hipLaunchKernelGGL(transpose_bf16_kernel, dim3(D_ / 32, HID_ / 32, E_), dim3(256), 0, stream,
                       w_down, wdT, HID_, D_, 1, 0, (long)D_ * HID_);

    // w_qkv (D x 3D) -> hi/lo bf16 planes (3D x D)
    hipLaunchKernelGGL(transpose_split_kernel, dim3(D3_ / 32, D_ / 32), dim3(256), 0, stream,
                       w_qkv, wqkvTh, wqkvTl, D_, D3_);

    // RoPE tables
    hipLaunchKernelGGL(rope_table_kernel, dim3((S_ * 32 + 255) / 256), dim3(256), 0, stream,
                       ctab, stab);

    // LN1 -> hi/lo bf16 planes
    hipLaunchKernelGGL(ln_kernel, dim3(T_), dim3(256), 0, stream,
                       x, ln1_g, ln1_b, (ushort_t*)nullptr, xnh, xnl);

    // QKV two-word bf16 MFMA GEMM: grid (24,16) = 384 blocks -> f32 qkv
    hipLaunchKernelGGL(qkv_mfma_kernel, dim3(D3_ / 128, T_ / 128), dim3(256), 0, stream,
                       xnh, xnl, wqkvTh, wqkvTl, qkvP0);

    // RoPE rotate q/k in place
    hipLaunchKernelGGL(rope_kernel, dim3(4, T_), dim3(256), 0, stream,
                       qkvP0, ctab, stab);

    // attention: split-K partials (two-word bf16 MFMA) + combine
    hipLaunchKernelGGL(attn_part_kernel, dim3(8, 16, 64), dim3(256), 0, stream,
                       qkvP0, Opart, Ml);
    hipLaunchKernelGGL(attn_combine_kernel, dim3(16, 64), dim3(256), 0, stream,
                       Opart, Ml, attnO);

    // W_O SGEMM + residual -> x1 AND out (down_idx accumulates on out)
    hipLaunchKernelGGL((sgemm_kernel<64>), dim3(D_ / 64, T_ / 64), dim3(256), 0, stream,
                       attnO, w_o, x, x1, out, T_, D_, D_);

    // LN2 (bf16)
    hipLaunchKernelGGL(ln_kernel, dim3(T_), dim3(256), 0, stream,
                       x1, ln2_g, ln2_b, xn2, (ushort_t*)nullptr, (ushort_t*)nullptr);

    // gating + routing + aux outputs
    hipLaunchKernelGGL(zero_route_kernel, dim3(1), dim3(64), 0, stream, cnt);
    hipLaunchKernelGGL(gate_kernel, dim3(T_), dim3(64), 0, stream,
                       xn2, gate_w, cnt, tok, wt, probs);
    hipLaunchKernelGGL(reduce_dist_kernel, dim3(1), dim3(256), 0, stream, probs, out);

    // MoE routed: fused gate+up (+silu), then weighted down (split-K=2)
    hipLaunchKernelGGL(gateup_idx_kernel, dim3(GU_ / 128, T_ / 128, E_), dim3(256), 0, stream,
                       xn2, wguT, cnt, tok, Hc);
    hipLaunchKernelGGL(down_idx_kernel, dim3(D_ / 128, T_ / 128, E_ * 2), dim3(256), 0, stream,
                       Hc, wdT, cnt, tok, wt, out);
}

// Round 4
// 639.590 us; speedup vs baseline: 1.3205x; 1.0572x over previous
//
#include <hip/hip_runtime.h>
#include <hip/hip_bf16.h>
#include <math.h>

// ---------------------------------------------------------------------------
// Shapes (fixed by the problem)
// ---------------------------------------------------------------------------
#define B_    4
#define S_    512
#define D_    1024
#define T_    2048          // B*S tokens
#define H_    16
#define HD_   64
#define E_    8
#define HID_  1792
#define D3_   3072
#define GU_   (2 * HID_)    // 3584 interleaved gate/up columns
#define NPART_ 72           // partial chunks per (b,h): sum_{qt<16} (qt/2+1)

typedef unsigned short ushort_t;
typedef __bf16 bf16x8 __attribute__((ext_vector_type(8)));
typedef float  floatx4 __attribute__((ext_vector_type(4)));

__constant__ int kPrefix[16] = {0,1,2,4,6,9,12,16,20,25,30,36,42,49,56,64};

__device__ inline float bf2f(ushort_t u) {
    return __uint_as_float(((unsigned)u) << 16);
}
__device__ inline ushort_t f2bf(float f) {
    __hip_bfloat16 h = __float2bfloat16(f);
    return __builtin_bit_cast(ushort_t, h);
}

// two-word bf16 split: x ~= hi + lo with combined rel error ~2^-17.
// hi = truncated-bf16(x) (exact prefix), lo = rne-bf16(x - hi).
__device__ __forceinline__ void split2(float x, ushort_t& h, ushort_t& l) {
    const unsigned ub = __float_as_uint(x);
    h = (ushort_t)(ub >> 16);
    l = f2bf(x - __uint_as_float(ub & 0xFFFF0000u));
}

// async 16B/lane global->LDS; lds dest wave-uniform base (+lane*16 by HW)
__device__ __forceinline__ void gl2lds16(const ushort_t* g, ushort_t* l) {
    __builtin_amdgcn_global_load_lds(
        (const __attribute__((address_space(1))) void*)g,
        (__attribute__((address_space(3))) void*)l, 16, 0, 0);
}

// ---------------------------------------------------------------------------
// Transpose + fp32->bf16: in (z,R,C) f32 -> out[z*outEstride + (c*mul+add)*R + r]
// ---------------------------------------------------------------------------
__global__ __launch_bounds__(256) void transpose_bf16_kernel(
    const float* __restrict__ in, ushort_t* __restrict__ out,
    int R, int C, int mul, int add, long outEstride)
{
    __shared__ float tile[32][33];
    const int bx = blockIdx.x * 32;           // c
    const int by = blockIdx.y * 32;           // r
    const size_t iofs = (size_t)blockIdx.z * R * C;
    const size_t oofs = (size_t)blockIdx.z * outEstride;
    const int tx = threadIdx.x & 31;
    const int ty = threadIdx.x >> 5;          // 0..7
#pragma unroll
    for (int i = 0; i < 4; i++) {
        int r = by + ty + i * 8;
        tile[ty + i * 8][tx] = in[iofs + (size_t)r * C + bx + tx];
    }
    __syncthreads();
#pragma unroll
    for (int i = 0; i < 4; i++) {
        int c = bx + ty + i * 8;
        out[oofs + (size_t)(c * mul + add) * R + by + tx] = f2bf(tile[tx][ty + i * 8]);
    }
}

// ---------------------------------------------------------------------------
// Transpose + fp32 -> two-word bf16 planes: in (R,C) f32 -> outh/outl[c*R + r]
// ---------------------------------------------------------------------------
__global__ __launch_bounds__(256) void transpose_split_kernel(
    const float* __restrict__ in, ushort_t* __restrict__ outh,
    ushort_t* __restrict__ outl, int R, int C)
{
    __shared__ float tile[32][33];
    const int bx = blockIdx.x * 32;           // c
    const int by = blockIdx.y * 32;           // r
    const int tx = threadIdx.x & 31;
    const int ty = threadIdx.x >> 5;          // 0..7
#pragma unroll
    for (int i = 0; i < 4; i++) {
        int r = by + ty + i * 8;
        tile[ty + i * 8][tx] = in[(size_t)r * C + bx + tx];
    }
    __syncthreads();
#pragma unroll
    for (int i = 0; i < 4; i++) {
        const int c = bx + ty + i * 8;
        const float v = tile[tx][ty + i * 8];
        ushort_t hh, ll;
        split2(v, hh, ll);
        outh[(size_t)c * R + by + tx] = hh;
        outl[(size_t)c * R + by + tx] = ll;
    }
}

// ---------------------------------------------------------------------------
// LayerNorm: x (rows x 1024) f32 -> optional bf16 out and/or hi/lo bf16 planes
// ---------------------------------------------------------------------------
__global__ __launch_bounds__(256) void ln_kernel(
    const float* __restrict__ x, const float* __restrict__ g,
    const float* __restrict__ b, ushort_t* __restrict__ outb,
    ushort_t* __restrict__ outh, ushort_t* __restrict__ outl)
{
    const int t = blockIdx.x;
    const int tid = threadIdx.x;
    const int wave = tid >> 6, lane = tid & 63;
    const float4 v = ((const float4*)(x + (size_t)t * D_))[tid];

    float s = v.x + v.y + v.z + v.w;
#pragma unroll
    for (int off = 32; off; off >>= 1) s += __shfl_xor(s, off);
    __shared__ float red1[4];
    __shared__ float red2[4];
    if (lane == 0) red1[wave] = s;
    __syncthreads();
    const float mu = (red1[0] + red1[1] + red1[2] + red1[3]) * (1.0f / D_);

    const float dx = v.x - mu, dy = v.y - mu, dz = v.z - mu, dw = v.w - mu;
    float vs = dx * dx + dy * dy + dz * dz + dw * dw;
#pragma unroll
    for (int off = 32; off; off >>= 1) vs += __shfl_xor(vs, off);
    if (lane == 0) red2[wave] = vs;
    __syncthreads();
    const float var = (red2[0] + red2[1] + red2[2] + red2[3]) * (1.0f / D_);
    const float rs = 1.0f / sqrtf(var + 1e-5f);

    const float4 gg = ((const float4*)g)[tid];
    const float4 bb = ((const float4*)b)[tid];
    float4 o;
    o.x = dx * rs * gg.x + bb.x;
    o.y = dy * rs * gg.y + bb.y;
    o.z = dz * rs * gg.z + bb.z;
    o.w = dw * rs * gg.w + bb.w;
    if (outb) {
        ushort4 ob;
        ob.x = f2bf(o.x); ob.y = f2bf(o.y); ob.z = f2bf(o.z); ob.w = f2bf(o.w);
        ((ushort4*)(outb + (size_t)t * D_))[tid] = ob;
    }
    if (outh) {
        ushort4 oh, ol;
        split2(o.x, oh.x, ol.x); split2(o.y, oh.y, ol.y);
        split2(o.z, oh.z, ol.z); split2(o.w, oh.w, ol.w);
        ((ushort4*)(outh + (size_t)t * D_))[tid] = oh;
        ((ushort4*)(outl + (size_t)t * D_))[tid] = ol;
    }
}

// ---------------------------------------------------------------------------
// Two-word bf16 MFMA GEMM: C[M x ncols] = (Ah+Al)[M x 1024] · (Bh+Bl)[N x 1024]^T
// (+ optional f32 residual, optional second output). 128x128 tile, BK=32,
// 4 waves, 4x4 16x16x32 MFMAs per wave, 3 per product (hh + lh + hl).
// Same fragment convention as gateup_idx_kernel (harness-verified).
// ---------------------------------------------------------------------------
__global__ __launch_bounds__(256) void gemm2w_kernel(
    const ushort_t* __restrict__ Ah, const ushort_t* __restrict__ Al,
    const ushort_t* __restrict__ Bh, const ushort_t* __restrict__ Bl,
    const float* __restrict__ res, float* __restrict__ C,
    float* __restrict__ C2, int ncols)
{
    const int row0 = blockIdx.y * 128, col0 = blockIdx.x * 128;

    __shared__ __align__(16) ushort_t Ash[128 * 32], Asl[128 * 32];
    __shared__ __align__(16) ushort_t Bsh[128 * 32], Bsl[128 * 32];
    const int tid = threadIdx.x, w = tid >> 6, lane = tid & 63;
    const int lr = lane >> 2, lc = (lane & 3) * 8;
    const int wm = (w >> 1) * 64, wn = (w & 1) * 64;
    const int lm = lane & 15, lq = lane >> 4;

    floatx4 acc[4][4] = {};

    const ushort_t* Aph = Ah + (size_t)(row0 + w * 16 + lr) * D_ + lc;
    const ushort_t* Apl = Al + (size_t)(row0 + w * 16 + lr) * D_ + lc;
    const ushort_t* Bph = Bh + (size_t)(col0 + w * 16 + lr) * D_ + lc;
    const ushort_t* Bpl = Bl + (size_t)(col0 + w * 16 + lr) * D_ + lc;
    ushort_t* lAh = Ash + w * 512;
    ushort_t* lAl = Asl + w * 512;
    ushort_t* lBh = Bsh + w * 512;
    ushort_t* lBl = Bsl + w * 512;

    for (int k0 = 0; k0 < D_; k0 += 32) {
        __syncthreads();
        gl2lds16(Aph + k0, lAh);
        gl2lds16(Aph + k0 + (size_t)64 * D_, lAh + 2048);
        gl2lds16(Apl + k0, lAl);
        gl2lds16(Apl + k0 + (size_t)64 * D_, lAl + 2048);
        gl2lds16(Bph + k0, lBh);
        gl2lds16(Bph + k0 + (size_t)64 * D_, lBh + 2048);
        gl2lds16(Bpl + k0, lBl);
        gl2lds16(Bpl + k0 + (size_t)64 * D_, lBl + 2048);
        __syncthreads();
        bf16x8 ah[4], al[4], bh16[4], bl16[4];
#pragma unroll
        for (int i = 0; i < 4; i++) {
            ah[i] = *(const bf16x8*)(Ash + (wm + i * 16 + lm) * 32 + lq * 8);
            al[i] = *(const bf16x8*)(Asl + (wm + i * 16 + lm) * 32 + lq * 8);
        }
#pragma unroll
        for (int j = 0; j < 4; j++) {
            bh16[j] = *(const bf16x8*)(Bsh + (wn + j * 16 + lm) * 32 + lq * 8);
            bl16[j] = *(const bf16x8*)(Bsl + (wn + j * 16 + lm) * 32 + lq * 8);
        }
#pragma unroll
        for (int i = 0; i < 4; i++)
#pragma unroll
            for (int j = 0; j < 4; j++) {
                acc[i][j] = __builtin_amdgcn_mfma_f32_16x16x32_bf16(ah[i], bh16[j], acc[i][j], 0, 0, 0);
                acc[i][j] = __builtin_amdgcn_mfma_f32_16x16x32_bf16(al[i], bh16[j], acc[i][j], 0, 0, 0);
                acc[i][j] = __builtin_amdgcn_mfma_f32_16x16x32_bf16(ah[i], bl16[j], acc[i][j], 0, 0, 0);
            }
    }

#pragma unroll
    for (int i = 0; i < 4; i++)
#pragma unroll
        for (int r = 0; r < 4; r++) {
            const int row = row0 + wm + i * 16 + lq * 4 + r;
#pragma unroll
            for (int j = 0; j < 4; j++) {
                const int col = col0 + wn + j * 16 + lm;
                const size_t idx = (size_t)row * ncols + col;
                float o = acc[i][j][r];
                if (res) o += res[idx];
                C[idx] = o;
                if (C2) C2[idx] = o;
            }
        }
}

// ---------------------------------------------------------------------------
// rope: rotate q/k cols of qkv in place. grid (4, T): thread handles 2 elems.
// ---------------------------------------------------------------------------
__global__ __launch_bounds__(256) void rope_kernel(
    float* __restrict__ P0,
    const float* __restrict__ ctab, const float* __restrict__ stab)
{
    const int t = blockIdx.y;
    const int c2 = blockIdx.x * 256 + threadIdx.x;   // 0..1023
    const int col = c2 * 2;                           // 0..2046 (q,k only)
    const size_t idx = (size_t)t * D3_ + col;
    const float2 a0 = *(const float2*)(P0 + idx);
    const int pair = (col & 63) >> 1;
    const int s = t & (S_ - 1);
    const float c = ctab[s * 32 + pair];
    const float sn = stab[s * 32 + pair];
    float2 o;
    o.x = a0.x * c - a0.y * sn;
    o.y = a0.x * sn + a0.y * c;
    *(float2*)(P0 + idx) = o;
}

// ---------------------------------------------------------------------------
// Routed fused gate+up MoE GEMM: rows gathered from per-expert token lists.
// ---------------------------------------------------------------------------
__global__ __launch_bounds__(256) void gateup_idx_kernel(
    const ushort_t* __restrict__ A, const ushort_t* __restrict__ Bgu,
    const int* __restrict__ cnt, const int* __restrict__ tok,
    ushort_t* __restrict__ Hc)
{
    const int e = blockIdx.z;
    const int cntE = cnt[e];
    const int row0 = blockIdx.y * 128;
    if (row0 >= cntE) return;
    const int col0 = blockIdx.x * 128;
    const ushort_t* Bt = Bgu + (size_t)e * GU_ * D_;
    ushort_t* Hp = Hc + (size_t)e * T_ * HID_;

    __shared__ __align__(16) ushort_t As[128 * 32];
    __shared__ __align__(16) ushort_t Bs[128 * 32];
    const int tid = threadIdx.x, w = tid >> 6, lane = tid & 63;
    const int lr = lane >> 2, lc = (lane & 3) * 8;
    const int wm = (w >> 1) * 64, wn = (w & 1) * 64;
    const int lm = lane & 15, lq = lane >> 4;

    floatx4 acc[4][4] = {};

    int r0c = row0 + w * 16 + lr;  if (r0c > cntE - 1) r0c = cntE - 1;
    int r1c = row0 + 64 + w * 16 + lr; if (r1c > cntE - 1) r1c = cntE - 1;
    const ushort_t* Ap0 = A + (size_t)tok[e * T_ + r0c] * D_ + lc;
    const ushort_t* Ap1 = A + (size_t)tok[e * T_ + r1c] * D_ + lc;
    const ushort_t* Bp = Bt + (size_t)(col0 + w * 16 + lr) * D_ + lc;
    ushort_t* lA = As + w * 512;
    ushort_t* lB = Bs + w * 512;

    for (int k0 = 0; k0 < D_; k0 += 32) {
        __syncthreads();
        gl2lds16(Ap0 + k0, lA);
        gl2lds16(Ap1 + k0, lA + 2048);
        gl2lds16(Bp + k0, lB);
        gl2lds16(Bp + k0 + (size_t)64 * D_, lB + 2048);
        __syncthreads();
        bf16x8 a[4], b[4];
#pragma unroll
        for (int i = 0; i < 4; i++)
            a[i] = *(const bf16x8*)(As + (wm + i * 16 + lm) * 32 + lq * 8);
#pragma unroll
        for (int j = 0; j < 4; j++)
            b[j] = *(const bf16x8*)(Bs + (wn + j * 16 + lm) * 32 + lq * 8);
#pragma unroll
        for (int i = 0; i < 4; i++)
#pragma unroll
            for (int j = 0; j < 4; j++)
                acc[i][j] = __builtin_amdgcn_mfma_f32_16x16x32_bf16(a[i], b[j], acc[i][j], 0, 0, 0);
    }

    // epilogue: adjacent lanes hold (gate, up) for the same hidden unit
#pragma unroll
    for (int i = 0; i < 4; i++)
#pragma unroll
        for (int j = 0; j < 4; j++)
#pragma unroll
            for (int r = 0; r < 4; r++) {
                const float v = acc[i][j][r];
                const float vp = __shfl_xor(v, 1);
                const float g = (lm & 1) ? vp : v;
                const float u = (lm & 1) ? v : vp;
                const float h = g / (1.f + __expf(-g)) * u;
                if (!(lm & 1)) {
                    const int row = row0 + wm + i * 16 + lq * 4 + r;
                    const int col = col0 + wn + j * 16 + lm;    // even
                    Hp[(size_t)row * HID_ + (col >> 1)] = f2bf(h);
                }
            }
}

// ---------------------------------------------------------------------------
// Routed MoE down GEMM, split-K: out[tok[r]] += wt[r] * (Hc[e] @ wd[e]^T).
// grid (8, 16, E*2): z -> (expert, k-slice of HID/2).
// ---------------------------------------------------------------------------
__global__ __launch_bounds__(256) void down_idx_kernel(
    const ushort_t* __restrict__ Hc, const ushort_t* __restrict__ Wd,
    const int* __restrict__ cnt, const int* __restrict__ tok,
    const float* __restrict__ wt, float* __restrict__ out)
{
    const int e = blockIdx.z >> 1;
    const int ks = blockIdx.z & 1;
    const int cntE = cnt[e];
    const int row0 = blockIdx.y * 128;
    if (row0 >= cntE) return;
    const int col0 = blockIdx.x * 128;
    const int kBegin = ks * (HID_ / 2);
    const ushort_t* A = Hc + (size_t)e * T_ * HID_;
    const ushort_t* Bt = Wd + (size_t)e * D_ * HID_;

    __shared__ __align__(16) ushort_t As[128 * 32];
    __shared__ __align__(16) ushort_t Bs[128 * 32];
    const int tid = threadIdx.x, w = tid >> 6, lane = tid & 63;
    const int lr = lane >> 2, lc = (lane & 3) * 8;
    const int wm = (w >> 1) * 64, wn = (w & 1) * 64;
    const int lm = lane & 15, lq = lane >> 4;

    floatx4 acc[4][4] = {};

    const ushort_t* Ap = A + (size_t)(row0 + w * 16 + lr) * HID_ + kBegin + lc;
    const ushort_t* Bp = Bt + (size_t)(col0 + w * 16 + lr) * HID_ + kBegin + lc;
    ushort_t* lA = As + w * 512;
    ushort_t* lB = Bs + w * 512;

    for (int k0 = 0; k0 < HID_ / 2; k0 += 32) {
        __syncthreads();
        gl2lds16(Ap + k0, lA);
        gl2lds16(Ap + k0 + (size_t)64 * HID_, lA + 2048);
        gl2lds16(Bp + k0, lB);
        gl2lds16(Bp + k0 + (size_t)64 * HID_, lB + 2048);
        __syncthreads();
        bf16x8 a[4], b[4];
#pragma unroll
        for (int i = 0; i < 4; i++)
            a[i] = *(const bf16x8*)(As + (wm + i * 16 + lm) * 32 + lq * 8);
#pragma unroll
        for (int j = 0; j < 4; j++)
            b[j] = *(const bf16x8*)(Bs + (wn + j * 16 + lm) * 32 + lq * 8);
#pragma unroll
        for (int i = 0; i < 4; i++)
#pragma unroll
            for (int j = 0; j < 4; j++)
                acc[i][j] = __builtin_amdgcn_mfma_f32_16x16x32_bf16(a[i], b[j], acc[i][j], 0, 0, 0);
    }

#pragma unroll
    for (int i = 0; i < 4; i++)
#pragma unroll
        for (int r = 0; r < 4; r++) {
            const int row = row0 + wm + i * 16 + lq * 4 + r;
            if (row < cntE) {
                const int t = tok[e * T_ + row];
                const float scale = wt[e * T_ + row];
#pragma unroll
                for (int j = 0; j < 4; j++) {
                    const int col = col0 + wn + j * 16 + lm;
                    atomicAdd(&out[(size_t)t * D_ + col], scale * acc[i][j][r]);
                }
            }
        }
}

// ---------------------------------------------------------------------------
// RoPE cos/sin tables (np f32 semantics via f64 pow/cos/sin)
// ---------------------------------------------------------------------------
__global__ __launch_bounds__(256) void rope_table_kernel(
    float* __restrict__ ctab, float* __restrict__ stab)
{
    const int i = blockIdx.x * 256 + threadIdx.x;   // S_*32
    if (i >= S_ * 32) return;
    const int s = i >> 5, p = i & 31;
    const double e = (double)(2 * p) / 64.0;
    const float pf = (float)pow(10000.0, e);
    const float invf = 1.0f / pf;
    const float fr = (float)s * invf;
    ctab[i] = (float)cos((double)fr);
    stab[i] = (float)sin((double)fr);
}

// ---------------------------------------------------------------------------
// Split-K flash attention, pass 1 — two-word bf16 MFMA, merged K/V LDS.
// Block: (kc, qt, bh), 256 thr = 4 waves. Wave w owns kv/d chunk w*16..+15.
// K and V^T time-share one LDS buffer: stage K -> QK MFMA -> barrier ->
// overwrite with V^T (from regs prefetched at entry) + softmax -> barrier ->
// PV. LDS 56.3 -> 37.9 KB => 4 blocks/CU (was 2).
// ---------------------------------------------------------------------------
__global__ __launch_bounds__(256, 4) void attn_part_kernel(
    const float* __restrict__ qkv, float* __restrict__ Opart,
    float* __restrict__ Ml)
{
    const int qt = blockIdx.y;
    const int kc = blockIdx.x;
    if (kc > (qt >> 1)) return;
    const int bh = blockIdx.z;                 // b*16+h
    const int b = bh >> 4, h = bh & 15;
    const int q0 = qt * 32;
    const int c0 = kc * 64;
    const int pidx = bh * NPART_ + kPrefix[qt] + kc;

    // bf16 hi/lo tiles, row stride 72 (pad 8) keeps b128 reads 16B-aligned
    __shared__ __align__(16) ushort_t qsh[32 * 72], qsl[32 * 72];  // Q rows (q, d)
    __shared__ __align__(16) ushort_t kvh[64 * 72], kvl[64 * 72];  // K rows, then V^T rows
    __shared__ __align__(16) ushort_t psh[32 * 72], psl[32 * 72];  // P rows (q, kv)
    __shared__ __align__(16) float redm[32][4];      // per-wave row max
    __shared__ __align__(16) float redl[32][4];      // per-wave row sum

    const int tid = threadIdx.x, w = tid >> 6, lane = tid & 63;
    const int lm = lane & 15, lq = lane >> 4;

    // ---- prefetch V (f32) into registers; consumed after the QK phase
    float4 vreg[4];
#pragma unroll
    for (int it = 0; it < 4; it++) {
        const int i = tid + it * 256;
        const int k = i >> 4, g = i & 15;
        vreg[it] = *(const float4*)(qkv + (size_t)(b * S_ + c0 + k) * D3_ + 2 * D_ + h * HD_ + g * 4);
    }

    // ---- stage Q (32x64 f32 -> hi/lo bf16); 8 elements per thread
    {
        const int row = tid >> 3, g = tid & 7;
        const float* src = qkv + (size_t)(b * S_ + q0 + row) * D3_ + h * HD_ + g * 8;
        const float4 v0 = *(const float4*)(src);
        const float4 v1 = *(const float4*)(src + 4);
        ushort4 h0, l0, h1, l1;
        split2(v0.x, h0.x, l0.x); split2(v0.y, h0.y, l0.y);
        split2(v0.z, h0.z, l0.z); split2(v0.w, h0.w, l0.w);
        split2(v1.x, h1.x, l1.x); split2(v1.y, h1.y, l1.y);
        split2(v1.z, h1.z, l1.z); split2(v1.w, h1.w, l1.w);
        *(ushort4*)(qsh + row * 72 + g * 8)     = h0;
        *(ushort4*)(qsh + row * 72 + g * 8 + 4) = h1;
        *(ushort4*)(qsl + row * 72 + g * 8)     = l0;
        *(ushort4*)(qsl + row * 72 + g * 8 + 4) = l1;
    }
    // ---- stage K (64x64 f32 -> hi/lo bf16) into the shared K/V buffer
#pragma unroll
    for (int it = 0; it < 2; it++) {
        const int i = tid + it * 256;
        const int row = i >> 3, g = i & 7;
        const float* src = qkv + (size_t)(b * S_ + c0 + row) * D3_ + D_ + h * HD_ + g * 8;
        const float4 v0 = *(const float4*)(src);
        const float4 v1 = *(const float4*)(src + 4);
        ushort4 h0, l0, h1, l1;
        split2(v0.x, h0.x, l0.x); split2(v0.y, h0.y, l0.y);
        split2(v0.z, h0.z, l0.z); split2(v0.w, h0.w, l0.w);
        split2(v1.x, h1.x, l1.x); split2(v1.y, h1.y, l1.y);
        split2(v1.z, h1.z, l1.z); split2(v1.w, h1.w, l1.w);
        *(ushort4*)(kvh + row * 72 + g * 8)     = h0;
        *(ushort4*)(kvh + row * 72 + g * 8 + 4) = h1;
        *(ushort4*)(kvl + row * 72 + g * 8)     = l0;
        *(ushort4*)(kvl + row * 72 + g * 8 + 4) = l1;
    }
    __syncthreads();

    // ---- scores: wave w -> S[32 q][16 kv] chunk; 3 MFMAs per product
    floatx4 acc[2] = {};
#pragma unroll
    for (int k0 = 0; k0 < 64; k0 += 32) {
        const bf16x8 bh16 = *(const bf16x8*)(kvh + (w * 16 + lm) * 72 + k0 + lq * 8);
        const bf16x8 bl16 = *(const bf16x8*)(kvl + (w * 16 + lm) * 72 + k0 + lq * 8);
#pragma unroll
        for (int i = 0; i < 2; i++) {
            const bf16x8 ah = *(const bf16x8*)(qsh + (i * 16 + lm) * 72 + k0 + lq * 8);
            const bf16x8 al = *(const bf16x8*)(qsl + (i * 16 + lm) * 72 + k0 + lq * 8);
            acc[i] = __builtin_amdgcn_mfma_f32_16x16x32_bf16(ah, bh16, acc[i], 0, 0, 0);
            acc[i] = __builtin_amdgcn_mfma_f32_16x16x32_bf16(al, bh16, acc[i], 0, 0, 0);
            acc[i] = __builtin_amdgcn_mfma_f32_16x16x32_bf16(ah, bl16, acc[i], 0, 0, 0);
        }
    }

    // ---- mask + scale, per-row max over this wave's 16 kv (lanes sharing lq)
    float sv[2][4];
    const int kvg = c0 + w * 16 + lm;
#pragma unroll
    for (int i = 0; i < 2; i++)
#pragma unroll
        for (int r = 0; r < 4; r++) {
            const int qg = q0 + i * 16 + lq * 4 + r;
            float v = (kvg <= qg) ? acc[i][r] * 0.125f : -INFINITY;
            sv[i][r] = v;
#pragma unroll
            for (int off = 1; off < 16; off <<= 1) v = fmaxf(v, __shfl_xor(v, off));
            if (lm == 0) redm[i * 16 + lq * 4 + r][w] = v;
        }
    __syncthreads();   // all K reads done; redm complete

    // ---- stage V transposed into the shared buffer (overwrites K)
#pragma unroll
    for (int it = 0; it < 4; it++) {
        const int i = tid + it * 256;
        const int k = i >> 4, g = i & 15;
        const float4 v = vreg[it];
        ushort_t hh, ll;
        split2(v.x, hh, ll); kvh[(g * 4 + 0) * 72 + k] = hh; kvl[(g * 4 + 0) * 72 + k] = ll;
        split2(v.y, hh, ll); kvh[(g * 4 + 1) * 72 + k] = hh; kvl[(g * 4 + 1) * 72 + k] = ll;
        split2(v.z, hh, ll); kvh[(g * 4 + 2) * 72 + k] = hh; kvl[(g * 4 + 2) * 72 + k] = ll;
        split2(v.w, hh, ll); kvh[(g * 4 + 3) * 72 + k] = hh; kvl[(g * 4 + 3) * 72 + k] = ll;
    }

    // ---- global (64-kv-chunk) row max, p = exp(s - M) f32, hi/lo split, sums
#pragma unroll
    for (int i = 0; i < 2; i++)
#pragma unroll
        for (int r = 0; r < 4; r++) {
            const int q = i * 16 + lq * 4 + r;
            const float4 m4 = *(const float4*)&redm[q][0];
            const float M = fmaxf(fmaxf(m4.x, m4.y), fmaxf(m4.z, m4.w));
            const float p = expf(sv[i][r] - M);
            ushort_t ph, pl;
            split2(p, ph, pl);
            psh[q * 72 + w * 16 + lm] = ph;
            psl[q * 72 + w * 16 + lm] = pl;
            float sum = p;
#pragma unroll
            for (int off = 1; off < 16; off <<= 1) sum += __shfl_xor(sum, off);
            if (lm == 0) redl[q][w] = sum;
        }
    __syncthreads();   // ps, V^T, redl ready

    // ---- write chunk m, l (matches attn_combine expectations)
    if (tid < 32) {
        const float4 m4 = *(const float4*)&redm[tid][0];
        const float4 l4 = *(const float4*)&redl[tid][0];
        Ml[(size_t)pidx * 64 + tid] = fmaxf(fmaxf(m4.x, m4.y), fmaxf(m4.z, m4.w));
        Ml[(size_t)pidx * 64 + 32 + tid] = l4.x + l4.y + l4.z + l4.w;
    }

    // ---- PV: O[32 q][16 d chunk w] = (Ph+Pl) · (Vh+Vl)^T, 3 MFMAs/product
    floatx4 acc2[2] = {};
#pragma unroll
    for (int k0 = 0; k0 < 64; k0 += 32) {
        const bf16x8 bh16 = *(const bf16x8*)(kvh + (w * 16 + lm) * 72 + k0 + lq * 8);
        const bf16x8 bl16 = *(const bf16x8*)(kvl + (w * 16 + lm) * 72 + k0 + lq * 8);
#pragma unroll
        for (int i = 0; i < 2; i++) {
            const bf16x8 ah = *(const bf16x8*)(psh + (i * 16 + lm) * 72 + k0 + lq * 8);
            const bf16x8 al = *(const bf16x8*)(psl + (i * 16 + lm) * 72 + k0 + lq * 8);
            acc2[i] = __builtin_amdgcn_mfma_f32_16x16x32_bf16(ah, bh16, acc2[i], 0, 0, 0);
            acc2[i] = __builtin_amdgcn_mfma_f32_16x16x32_bf16(al, bh16, acc2[i], 0, 0, 0);
            acc2[i] = __builtin_amdgcn_mfma_f32_16x16x32_bf16(ah, bl16, acc2[i], 0, 0, 0);
        }
    }
#pragma unroll
    for (int i = 0; i < 2; i++)
#pragma unroll
        for (int r = 0; r < 4; r++)
            Opart[((size_t)pidx * 32 + i * 16 + lq * 4 + r) * 64 + w * 16 + lm] = acc2[i][r];
}

// ---------------------------------------------------------------------------
// Split-K flash attention, pass 2: combine <=8 partials per (bh,qt).
// Emits attn output as hi/lo bf16 planes for the W_O MFMA GEMM.
// ---------------------------------------------------------------------------
__global__ __launch_bounds__(256) void attn_combine_kernel(
    const float* __restrict__ Opart, const float* __restrict__ Ml,
    ushort_t* __restrict__ aoh, ushort_t* __restrict__ aol)
{
    const int qt = blockIdx.x, bh = blockIdx.y;
    const int b = bh >> 4, h = bh & 15;
    const int nchunk = (qt >> 1) + 1;
    const int base = bh * NPART_ + kPrefix[qt];
    const int tid = threadIdx.x;
    const int qrow = tid >> 3;            // 0..31
    const int d0 = (tid & 7) * 8;         // 0..56

    float M = -INFINITY;
    for (int c = 0; c < nchunk; c++)
        M = fmaxf(M, Ml[(size_t)(base + c) * 64 + qrow]);

    float L = 0.f;
    float o[8] = {0, 0, 0, 0, 0, 0, 0, 0};
    for (int c = 0; c < nchunk; c++) {
        const float mc = Ml[(size_t)(base + c) * 64 + qrow];
        const float lc = Ml[(size_t)(base + c) * 64 + 32 + qrow];
        const float w = (mc == -INFINITY) ? 0.f : expf(mc - M);
        L = fmaf(lc, w, L);
        const size_t ob = ((size_t)(base + c) * 32 + qrow) * 64 + d0;
        const float4 a0 = *(const float4*)(Opart + ob);
        const float4 a1 = *(const float4*)(Opart + ob + 4);
        o[0] = fmaf(a0.x, w, o[0]); o[1] = fmaf(a0.y, w, o[1]);
        o[2] = fmaf(a0.z, w, o[2]); o[3] = fmaf(a0.w, w, o[3]);
        o[4] = fmaf(a1.x, w, o[4]); o[5] = fmaf(a1.y, w, o[5]);
        o[6] = fmaf(a1.z, w, o[6]); o[7] = fmaf(a1.w, w, o[7]);
    }
    const float inv = 1.f / L;
    const int t = b * S_ + qt * 32 + qrow;
    const size_t obase = (size_t)t * D_ + h * HD_ + d0;
    ushort4 h0, l0, h1, l1;
    split2(o[0] * inv, h0.x, l0.x); split2(o[1] * inv, h0.y, l0.y);
    split2(o[2] * inv, h0.z, l0.z); split2(o[3] * inv, h0.w, l0.w);
    split2(o[4] * inv, h1.x, l1.x); split2(o[5] * inv, h1.y, l1.y);
    split2(o[6] * inv, h1.z, l1.z); split2(o[7] * inv, h1.w, l1.w);
    *(ushort4*)(aoh + obase)     = h0;
    *(ushort4*)(aoh + obase + 4) = h1;
    *(ushort4*)(aol + obase)     = l0;
    *(ushort4*)(aol + obase + 4) = l1;
}

// ---------------------------------------------------------------------------
// Gating + routing. bf16-rounded logits, top-2 lowest-index tie-break.
// ---------------------------------------------------------------------------
__global__ __launch_bounds__(64) void gate_kernel(
    const ushort_t* __restrict__ xn2, const float* __restrict__ gate_w,
    int* __restrict__ cnt, int* __restrict__ tok, float* __restrict__ wt,
    float* __restrict__ probs)
{
    const int t = blockIdx.x;
    const int lane = threadIdx.x;
    float acc[8] = {0, 0, 0, 0, 0, 0, 0, 0};
    for (int d = lane; d < D_; d += 64) {
        const float xv = bf2f(xn2[(size_t)t * D_ + d]);
        const float4 g0 = ((const float4*)(gate_w + d * 8))[0];
        const float4 g1 = ((const float4*)(gate_w + d * 8))[1];
        acc[0] = fmaf(xv, bf2f(f2bf(g0.x)), acc[0]);
        acc[1] = fmaf(xv, bf2f(f2bf(g0.y)), acc[1]);
        acc[2] = fmaf(xv, bf2f(f2bf(g0.z)), acc[2]);
        acc[3] = fmaf(xv, bf2f(f2bf(g0.w)), acc[3]);
        acc[4] = fmaf(xv, bf2f(f2bf(g1.x)), acc[4]);
        acc[5] = fmaf(xv, bf2f(f2bf(g1.y)), acc[5]);
        acc[6] = fmaf(xv, bf2f(f2bf(g1.z)), acc[6]);
        acc[7] = fmaf(xv, bf2f(f2bf(g1.w)), acc[7]);
    }
#pragma unroll
    for (int e = 0; e < 8; e++) {
#pragma unroll
        for (int off = 32; off; off >>= 1) acc[e] += __shfl_xor(acc[e], off);
        acc[e] = bf2f(f2bf(acc[e]));   // bf16 result of the bf16 matmul
    }

    if (lane == 0) {
        int i1 = 0;
        for (int e = 1; e < 8; e++) if (acc[e] > acc[i1]) i1 = e;
        int i2 = (i1 == 0) ? 1 : 0;
        for (int e = 0; e < 8; e++) if (e != i1 && acc[e] > acc[i2]) i2 = e;
        const float e2 = expf(acc[i2] - acc[i1]);
        const float w1 = 1.f / (1.f + e2);
        const float w2 = e2 * w1;
        const int p1 = atomicAdd(&cnt[i1], 1);
        tok[i1 * T_ + p1] = t; wt[i1 * T_ + p1] = w1;
        const int p2 = atomicAdd(&cnt[i2], 1);
        tok[i2 * T_ + p2] = t; wt[i2 * T_ + p2] = w2;
        const float mx = acc[i1];
        float se = 0.f, pe[8];
        for (int e = 0; e < 8; e++) { pe[e] = expf(acc[e] - mx); se += pe[e]; }
        const float inv = 1.f / se;
        for (int e = 0; e < 8; e++) probs[t * 8 + e] = pe[e] * inv;
    }
}

__global__ void zero_route_kernel(int* __restrict__ cnt)
{
    if (threadIdx.x < 8) cnt[threadIdx.x] = 0;
}

// ---------------------------------------------------------------------------
// dist = probs.mean(0); lb = E * sum(dist^2); writes out tail.
// ---------------------------------------------------------------------------
__global__ __launch_bounds__(256) void reduce_dist_kernel(
    const float* __restrict__ probs, float* __restrict__ out)
{
    __shared__ float part[256];
    __shared__ float dist8[8];
    const int tid = threadIdx.x;
    const int e = tid & 7, chunk = tid >> 3;   // 32 chunks
    float s = 0.f;
    for (int t = chunk; t < T_; t += 32) s += probs[t * 8 + e];
    part[tid] = s;
    __syncthreads();
    if (tid < 8) {
        float tot = 0.f;
        for (int c = 0; c < 32; c++) tot += part[c * 8 + tid];
        const float dv = tot * (1.0f / T_);
        dist8[tid] = dv;
        out[(size_t)T_ * D_ + 1 + tid] = dv;
    }
    __syncthreads();
    if (tid == 0) {
        float s2 = 0.f;
        for (int k = 0; k < 8; k++) s2 += dist8[k] * dist8[k];
        out[(size_t)T_ * D_] = (float)E_ * s2;
    }
}

// ---------------------------------------------------------------------------
// Launch
// ---------------------------------------------------------------------------
extern "C" void kernel_launch(void* const* d_in, const int* in_sizes, int n_in,
                              void* d_out, int out_size, void* d_ws, size_t ws_size,
                              hipStream_t stream)
{
    const float* x      = (const float*)d_in[0];
    const float* ln1_g  = (const float*)d_in[1];
    const float* ln1_b  = (const float*)d_in[2];
    const float* ln2_g  = (const float*)d_in[3];
    const float* ln2_b  = (const float*)d_in[4];
    const float* w_qkv  = (const float*)d_in[5];
    const float* w_o    = (const float*)d_in[6];
    const float* gate_w = (const float*)d_in[7];
    const float* w_gate = (const float*)d_in[8];
    const float* w_up   = (const float*)d_in[9];
    const float* w_down = (const float*)d_in[10];
    float* out = (float*)d_out;

    char* ws = (char*)d_ws;
    size_t off = 0;
    auto alloc = [&](size_t bytes) { size_t o = off; off += (bytes + 255) & ~(size_t)255; return o; };
    // persistent-through-MoE region
    ushort_t* wguT  = (ushort_t*)(ws + alloc((size_t)E_ * GU_ * D_ * 2));   // 58.7 MB
    ushort_t* wdT   = (ushort_t*)(ws + alloc((size_t)E_ * D_ * HID_ * 2));  // 29.4 MB
    ushort_t* xnh   = (ushort_t*)(ws + alloc((size_t)T_ * D_ * 4));         // hi+lo planes
    ushort_t* xnl   = xnh + (size_t)T_ * D_;
    ushort_t* xn2   = (ushort_t*)(ws + alloc((size_t)T_ * D_ * 2));
    int*      cnt   = (int*)     (ws + alloc(64));
    int*      tok   = (int*)     (ws + alloc((size_t)E_ * T_ * 4));
    float*    wt    = (float*)   (ws + alloc((size_t)E_ * T_ * 4));
    float*    probs = (float*)   (ws + alloc((size_t)T_ * E_ * 4));
    float*    ctab  = (float*)   (ws + alloc((size_t)S_ * 32 * 4));
    float*    stab  = (float*)   (ws + alloc((size_t)S_ * 32 * 4));
    // scratch union (64.1 MB peak, aliased by lifetime):
    //   phase A: qkvP0 [0,25.2) + wqkvT hi/lo [25.2,37.8)   (QKV MFMA GEMM)
    //   phase B: qkv=P0 [0,25.2) + Opart [25.2,63) + Ml [63,64.1)
    //   phase C: aoh [0,4) aol [4,8) + x1 [8,16) + woT hi/lo [16,24) + Opart/Ml live until combine
    //   phase D: Hc [0,58.7)
    const size_t qkvBytes   = (size_t)T_ * D3_ * 4;
    const size_t opartBytes = (size_t)64 * NPART_ * 32 * 64 * 4;
    const size_t mlBytes    = (size_t)64 * NPART_ * 64 * 4;
    const size_t scratch0 = alloc(qkvBytes + opartBytes + mlBytes);
    float*    qkvP0 = (float*)   (ws + scratch0);
    ushort_t* wqkvTh= (ushort_t*)(ws + scratch0 + qkvBytes);          // dead before Opart
    ushort_t* wqkvTl= wqkvTh + (size_t)D3_ * D_;
    float*    Opart = (float*)   (ws + scratch0 + qkvBytes);
    float*    Ml    = (float*)   (ws + scratch0 + qkvBytes + opartBytes);
    ushort_t* aoh   = (ushort_t*)(ws + scratch0);                     // [0,4)  alias dead qkv
    ushort_t* aol   = aoh + (size_t)T_ * D_;                          // [4,8)
    float*    x1    = (float*)   (ws + scratch0 + (size_t)T_ * D_ * 4);          // [8,16)
    ushort_t* woTh  = (ushort_t*)(ws + scratch0 + (size_t)T_ * D_ * 8);          // [16,20)
    ushort_t* woTl  = woTh + (size_t)D_ * D_;                                     // [20,24)
    ushort_t* Hc    = (ushort_t*)(ws + scratch0);                     // alias all
    (void)ws_size; (void)in_sizes; (void)n_in; (void)out_size;

    // weight transposes -> bf16 (N x K); gate/up interleaved into wguT
    hipLaunchKernelGGL(transpose_bf16_kernel, dim3(HID_ / 32, D_ / 32, E_), dim3(256), 0, stream,
                       w_gate, wguT, D_, HID_, 2, 0, (long)GU_ * D_);
    hipLaunchKernelGGL(transpose_bf16_kernel, dim3(HID_ / 32, D_ / 32, E_), dim3(256), 0, stream,
                       w_up, wguT, D_, HID_, 2, 1, (long)GU_ * D_);
    hipLaunchKernelGGL(transpose_bf16_kernel, dim3(D_ / 32, HID_ / 32, E_), dim3(256), 0, stream,
                       w_down, wdT, HID_, D_, 1, 0, (long)D_ * HID_);

    // w_qkv (D x 3D) -> hi/lo bf16 planes (3D x D)
    hipLaunchKernelGGL(transpose_split_kernel, dim3(D3_ / 32, D_ / 32), dim3(256), 0, stream,
                       w_qkv, wqkvTh, wqkvTl, D_, D3_);

    // RoPE tables
    hipLaunchKernelGGL(rope_table_kernel, dim3((S_ * 32 + 255) / 256), dim3(256), 0, stream,
                       ctab, stab);

    // LN1 -> hi/lo bf16 planes
    hipLaunchKernelGGL(ln_kernel, dim3(T_), dim3(256), 0, stream,
                       x, ln1_g, ln1_b, (ushort_t*)nullptr, xnh, xnl);

    // QKV two-word bf16 MFMA GEMM: grid (24,16) -> f32 qkv
    hipLaunchKernelGGL(gemm2w_kernel, dim3(D3_ / 128, T_ / 128), dim3(256), 0, stream,
                       xnh, xnl, wqkvTh, wqkvTl, (const float*)nullptr, qkvP0,
                       (float*)nullptr, D3_);

    // RoPE rotate q/k in place
    hipLaunchKernelGGL(rope_kernel, dim3(4, T_), dim3(256), 0, stream,
                       qkvP0, ctab, stab);

    // attention: split-K partials (two-word bf16 MFMA, merged K/V LDS)
    hipLaunchKernelGGL(attn_part_kernel, dim3(8, 16, 64), dim3(256), 0, stream,
                       qkvP0, Opart, Ml);

    // w_o (D x D) -> hi/lo bf16 planes (D x D); qkvP0 dead now
    hipLaunchKernelGGL(transpose_split_kernel, dim3(D_ / 32, D_ / 32), dim3(256), 0, stream,
                       w_o, woTh, woTl, D_, D_);

    // combine partials -> attn output hi/lo planes
    hipLaunchKernelGGL(attn_combine_kernel, dim3(16, 64), dim3(256), 0, stream,
                       Opart, Ml, aoh, aol);

    // W_O two-word bf16 MFMA GEMM + residual -> x1 AND out
    hipLaunchKernelGGL(gemm2w_kernel, dim3(D_ / 128, T_ / 128), dim3(256), 0, stream,
                       aoh, aol, woTh, woTl, x, x1, out, D_);

    // LN2 (bf16)
    hipLaunchKernelGGL(ln_kernel, dim3(T_), dim3(256), 0, stream,
                       x1, ln2_g, ln2_b, xn2, (ushort_t*)nullptr, (ushort_t*)nullptr);

    // gating + routing + aux outputs
    hipLaunchKernelGGL(zero_route_kernel, dim3(1), dim3(64), 0, stream, cnt);
    hipLaunchKernelGGL(gate_kernel, dim3(T_), dim3(64), 0, stream,
                       xn2, gate_w, cnt, tok, wt, probs);
    hipLaunchKernelGGL(reduce_dist_kernel, dim3(1), dim3(256), 0, stream, probs, out);

    // MoE routed: fused gate+up (+silu), then weighted down (split-K=2)
    hipLaunchKernelGGL(gateup_idx_kernel, dim3(GU_ / 128, T_ / 128, E_), dim3(256), 0, stream,
                       xn2, wguT, cnt, tok, Hc);
    hipLaunchKernelGGL(down_idx_kernel, dim3(D_ / 128, T_ / 128, E_ * 2), dim3(256), 0, stream,
                       Hc, wdT, cnt, tok, wt, out);
}

// Round 5
// 620.662 us; speedup vs baseline: 1.3608x; 1.0305x over previous
//
#include <hip/hip_runtime.h>
#include <hip/hip_bf16.h>
#include <math.h>

// ---------------------------------------------------------------------------
// Shapes (fixed by the problem)
// ---------------------------------------------------------------------------
#define B_    4
#define S_    512
#define D_    1024
#define T_    2048          // B*S tokens
#define H_    16
#define HD_   64
#define E_    8
#define HID_  1792
#define D3_   3072
#define GU_   (2 * HID_)    // 3584 interleaved gate/up columns

typedef unsigned short ushort_t;
typedef __bf16 bf16x8 __attribute__((ext_vector_type(8)));
typedef float  floatx4 __attribute__((ext_vector_type(4)));

__device__ inline float bf2f(ushort_t u) {
    return __uint_as_float(((unsigned)u) << 16);
}
__device__ inline ushort_t f2bf(float f) {
    __hip_bfloat16 h = __float2bfloat16(f);
    return __builtin_bit_cast(ushort_t, h);
}

// two-word bf16 split: x ~= hi + lo with combined rel error ~2^-17.
// hi = truncated-bf16(x) (exact prefix), lo = rne-bf16(x - hi).
__device__ __forceinline__ void split2(float x, ushort_t& h, ushort_t& l) {
    const unsigned ub = __float_as_uint(x);
    h = (ushort_t)(ub >> 16);
    l = f2bf(x - __uint_as_float(ub & 0xFFFF0000u));
}

// async 16B/lane global->LDS; lds dest wave-uniform base (+lane*16 by HW)
__device__ __forceinline__ void gl2lds16(const ushort_t* g, ushort_t* l) {
    __builtin_amdgcn_global_load_lds(
        (const __attribute__((address_space(1))) void*)g,
        (__attribute__((address_space(3))) void*)l, 16, 0, 0);
}

// ---------------------------------------------------------------------------
// Transpose + fp32->bf16: in (z,R,C) f32 -> out[z*outEstride + (c*mul+add)*R + r]
// ---------------------------------------------------------------------------
__global__ __launch_bounds__(256) void transpose_bf16_kernel(
    const float* __restrict__ in, ushort_t* __restrict__ out,
    int R, int C, int mul, int add, long outEstride)
{
    __shared__ float tile[32][33];
    const int bx = blockIdx.x * 32;           // c
    const int by = blockIdx.y * 32;           // r
    const size_t iofs = (size_t)blockIdx.z * R * C;
    const size_t oofs = (size_t)blockIdx.z * outEstride;
    const int tx = threadIdx.x & 31;
    const int ty = threadIdx.x >> 5;          // 0..7
#pragma unroll
    for (int i = 0; i < 4; i++) {
        int r = by + ty + i * 8;
        tile[ty + i * 8][tx] = in[iofs + (size_t)r * C + bx + tx];
    }
    __syncthreads();
#pragma unroll
    for (int i = 0; i < 4; i++) {
        int c = bx + ty + i * 8;
        out[oofs + (size_t)(c * mul + add) * R + by + tx] = f2bf(tile[tx][ty + i * 8]);
    }
}

// ---------------------------------------------------------------------------
// Transpose + fp32 -> two-word bf16 planes: in (R,C) f32 -> outh/outl[c*R + r]
// ---------------------------------------------------------------------------
__global__ __launch_bounds__(256) void transpose_split_kernel(
    const float* __restrict__ in, ushort_t* __restrict__ outh,
    ushort_t* __restrict__ outl, int R, int C)
{
    __shared__ float tile[32][33];
    const int bx = blockIdx.x * 32;           // c
    const int by = blockIdx.y * 32;           // r
    const int tx = threadIdx.x & 31;
    const int ty = threadIdx.x >> 5;          // 0..7
#pragma unroll
    for (int i = 0; i < 4; i++) {
        int r = by + ty + i * 8;
        tile[ty + i * 8][tx] = in[(size_t)r * C + bx + tx];
    }
    __syncthreads();
#pragma unroll
    for (int i = 0; i < 4; i++) {
        const int c = bx + ty + i * 8;
        const float v = tile[tx][ty + i * 8];
        ushort_t hh, ll;
        split2(v, hh, ll);
        outh[(size_t)c * R + by + tx] = hh;
        outl[(size_t)c * R + by + tx] = ll;
    }
}

// ---------------------------------------------------------------------------
// LayerNorm: x (rows x 1024) f32 -> optional bf16 out and/or hi/lo bf16 planes
// ---------------------------------------------------------------------------
__global__ __launch_bounds__(256) void ln_kernel(
    const float* __restrict__ x, const float* __restrict__ g,
    const float* __restrict__ b, ushort_t* __restrict__ outb,
    ushort_t* __restrict__ outh, ushort_t* __restrict__ outl)
{
    const int t = blockIdx.x;
    const int tid = threadIdx.x;
    const int wave = tid >> 6, lane = tid & 63;
    const float4 v = ((const float4*)(x + (size_t)t * D_))[tid];

    float s = v.x + v.y + v.z + v.w;
#pragma unroll
    for (int off = 32; off; off >>= 1) s += __shfl_xor(s, off);
    __shared__ float red1[4];
    __shared__ float red2[4];
    if (lane == 0) red1[wave] = s;
    __syncthreads();
    const float mu = (red1[0] + red1[1] + red1[2] + red1[3]) * (1.0f / D_);

    const float dx = v.x - mu, dy = v.y - mu, dz = v.z - mu, dw = v.w - mu;
    float vs = dx * dx + dy * dy + dz * dz + dw * dw;
#pragma unroll
    for (int off = 32; off; off >>= 1) vs += __shfl_xor(vs, off);
    if (lane == 0) red2[wave] = vs;
    __syncthreads();
    const float var = (red2[0] + red2[1] + red2[2] + red2[3]) * (1.0f / D_);
    const float rs = 1.0f / sqrtf(var + 1e-5f);

    const float4 gg = ((const float4*)g)[tid];
    const float4 bb = ((const float4*)b)[tid];
    float4 o;
    o.x = dx * rs * gg.x + bb.x;
    o.y = dy * rs * gg.y + bb.y;
    o.z = dz * rs * gg.z + bb.z;
    o.w = dw * rs * gg.w + bb.w;
    if (outb) {
        ushort4 ob;
        ob.x = f2bf(o.x); ob.y = f2bf(o.y); ob.z = f2bf(o.z); ob.w = f2bf(o.w);
        ((ushort4*)(outb + (size_t)t * D_))[tid] = ob;
    }
    if (outh) {
        ushort4 oh, ol;
        split2(o.x, oh.x, ol.x); split2(o.y, oh.y, ol.y);
        split2(o.z, oh.z, ol.z); split2(o.w, oh.w, ol.w);
        ((ushort4*)(outh + (size_t)t * D_))[tid] = oh;
        ((ushort4*)(outl + (size_t)t * D_))[tid] = ol;
    }
}

// ---------------------------------------------------------------------------
// Two-word bf16 MFMA GEMM: C[M x ncols] = (Ah+Al)[M x 1024] · (Bh+Bl)[N x 1024]^T
// (+ optional f32 residual, optional second output). 128x128 tile, BK=32,
// 4 waves, 4x4 16x16x32 MFMAs per wave, 3 per product (hh + lh + hl).
// ---------------------------------------------------------------------------
__global__ __launch_bounds__(256) void gemm2w_kernel(
    const ushort_t* __restrict__ Ah, const ushort_t* __restrict__ Al,
    const ushort_t* __restrict__ Bh, const ushort_t* __restrict__ Bl,
    const float* __restrict__ res, float* __restrict__ C,
    float* __restrict__ C2, int ncols)
{
    const int row0 = blockIdx.y * 128, col0 = blockIdx.x * 128;

    __shared__ __align__(16) ushort_t Ash[128 * 32], Asl[128 * 32];
    __shared__ __align__(16) ushort_t Bsh[128 * 32], Bsl[128 * 32];
    const int tid = threadIdx.x, w = tid >> 6, lane = tid & 63;
    const int lr = lane >> 2, lc = (lane & 3) * 8;
    const int wm = (w >> 1) * 64, wn = (w & 1) * 64;
    const int lm = lane & 15, lq = lane >> 4;

    floatx4 acc[4][4] = {};

    const ushort_t* Aph = Ah + (size_t)(row0 + w * 16 + lr) * D_ + lc;
    const ushort_t* Apl = Al + (size_t)(row0 + w * 16 + lr) * D_ + lc;
    const ushort_t* Bph = Bh + (size_t)(col0 + w * 16 + lr) * D_ + lc;
    const ushort_t* Bpl = Bl + (size_t)(col0 + w * 16 + lr) * D_ + lc;
    ushort_t* lAh = Ash + w * 512;
    ushort_t* lAl = Asl + w * 512;
    ushort_t* lBh = Bsh + w * 512;
    ushort_t* lBl = Bsl + w * 512;

    for (int k0 = 0; k0 < D_; k0 += 32) {
        __syncthreads();
        gl2lds16(Aph + k0, lAh);
        gl2lds16(Aph + k0 + (size_t)64 * D_, lAh + 2048);
        gl2lds16(Apl + k0, lAl);
        gl2lds16(Apl + k0 + (size_t)64 * D_, lAl + 2048);
        gl2lds16(Bph + k0, lBh);
        gl2lds16(Bph + k0 + (size_t)64 * D_, lBh + 2048);
        gl2lds16(Bpl + k0, lBl);
        gl2lds16(Bpl + k0 + (size_t)64 * D_, lBl + 2048);
        __syncthreads();
        bf16x8 ah[4], al[4], bh16[4], bl16[4];
#pragma unroll
        for (int i = 0; i < 4; i++) {
            ah[i] = *(const bf16x8*)(Ash + (wm + i * 16 + lm) * 32 + lq * 8);
            al[i] = *(const bf16x8*)(Asl + (wm + i * 16 + lm) * 32 + lq * 8);
        }
#pragma unroll
        for (int j = 0; j < 4; j++) {
            bh16[j] = *(const bf16x8*)(Bsh + (wn + j * 16 + lm) * 32 + lq * 8);
            bl16[j] = *(const bf16x8*)(Bsl + (wn + j * 16 + lm) * 32 + lq * 8);
        }
#pragma unroll
        for (int i = 0; i < 4; i++)
#pragma unroll
            for (int j = 0; j < 4; j++) {
                acc[i][j] = __builtin_amdgcn_mfma_f32_16x16x32_bf16(ah[i], bh16[j], acc[i][j], 0, 0, 0);
                acc[i][j] = __builtin_amdgcn_mfma_f32_16x16x32_bf16(al[i], bh16[j], acc[i][j], 0, 0, 0);
                acc[i][j] = __builtin_amdgcn_mfma_f32_16x16x32_bf16(ah[i], bl16[j], acc[i][j], 0, 0, 0);
            }
    }

#pragma unroll
    for (int i = 0; i < 4; i++)
#pragma unroll
        for (int r = 0; r < 4; r++) {
            const int row = row0 + wm + i * 16 + lq * 4 + r;
#pragma unroll
            for (int j = 0; j < 4; j++) {
                const int col = col0 + wn + j * 16 + lm;
                const size_t idx = (size_t)row * ncols + col;
                float o = acc[i][j][r];
                if (res) o += res[idx];
                C[idx] = o;
                if (C2) C2[idx] = o;
            }
        }
}

// ---------------------------------------------------------------------------
// rope: rotate q/k cols of qkv in place. grid (4, T): thread handles 2 elems.
// ---------------------------------------------------------------------------
__global__ __launch_bounds__(256) void rope_kernel(
    float* __restrict__ P0,
    const float* __restrict__ ctab, const float* __restrict__ stab)
{
    const int t = blockIdx.y;
    const int c2 = blockIdx.x * 256 + threadIdx.x;   // 0..1023
    const int col = c2 * 2;                           // 0..2046 (q,k only)
    const size_t idx = (size_t)t * D3_ + col;
    const float2 a0 = *(const float2*)(P0 + idx);
    const int pair = (col & 63) >> 1;
    const int s = t & (S_ - 1);
    const float c = ctab[s * 32 + pair];
    const float sn = stab[s * 32 + pair];
    float2 o;
    o.x = a0.x * c - a0.y * sn;
    o.y = a0.x * sn + a0.y * c;
    *(float2*)(P0 + idx) = o;
}

// ---------------------------------------------------------------------------
// Routed fused gate+up MoE GEMM: rows gathered from per-expert token lists.
// ---------------------------------------------------------------------------
__global__ __launch_bounds__(256) void gateup_idx_kernel(
    const ushort_t* __restrict__ A, const ushort_t* __restrict__ Bgu,
    const int* __restrict__ cnt, const int* __restrict__ tok,
    ushort_t* __restrict__ Hc)
{
    const int e = blockIdx.z;
    const int cntE = cnt[e];
    const int row0 = blockIdx.y * 128;
    if (row0 >= cntE) return;
    const int col0 = blockIdx.x * 128;
    const ushort_t* Bt = Bgu + (size_t)e * GU_ * D_;
    ushort_t* Hp = Hc + (size_t)e * T_ * HID_;

    __shared__ __align__(16) ushort_t As[128 * 32];
    __shared__ __align__(16) ushort_t Bs[128 * 32];
    const int tid = threadIdx.x, w = tid >> 6, lane = tid & 63;
    const int lr = lane >> 2, lc = (lane & 3) * 8;
    const int wm = (w >> 1) * 64, wn = (w & 1) * 64;
    const int lm = lane & 15, lq = lane >> 4;

    floatx4 acc[4][4] = {};

    int r0c = row0 + w * 16 + lr;  if (r0c > cntE - 1) r0c = cntE - 1;
    int r1c = row0 + 64 + w * 16 + lr; if (r1c > cntE - 1) r1c = cntE - 1;
    const ushort_t* Ap0 = A + (size_t)tok[e * T_ + r0c] * D_ + lc;
    const ushort_t* Ap1 = A + (size_t)tok[e * T_ + r1c] * D_ + lc;
    const ushort_t* Bp = Bt + (size_t)(col0 + w * 16 + lr) * D_ + lc;
    ushort_t* lA = As + w * 512;
    ushort_t* lB = Bs + w * 512;

    for (int k0 = 0; k0 < D_; k0 += 32) {
        __syncthreads();
        gl2lds16(Ap0 + k0, lA);
        gl2lds16(Ap1 + k0, lA + 2048);
        gl2lds16(Bp + k0, lB);
        gl2lds16(Bp + k0 + (size_t)64 * D_, lB + 2048);
        __syncthreads();
        bf16x8 a[4], b[4];
#pragma unroll
        for (int i = 0; i < 4; i++)
            a[i] = *(const bf16x8*)(As + (wm + i * 16 + lm) * 32 + lq * 8);
#pragma unroll
        for (int j = 0; j < 4; j++)
            b[j] = *(const bf16x8*)(Bs + (wn + j * 16 + lm) * 32 + lq * 8);
#pragma unroll
        for (int i = 0; i < 4; i++)
#pragma unroll
            for (int j = 0; j < 4; j++)
                acc[i][j] = __builtin_amdgcn_mfma_f32_16x16x32_bf16(a[i], b[j], acc[i][j], 0, 0, 0);
    }

    // epilogue: adjacent lanes hold (gate, up) for the same hidden unit
#pragma unroll
    for (int i = 0; i < 4; i++)
#pragma unroll
        for (int j = 0; j < 4; j++)
#pragma unroll
            for (int r = 0; r < 4; r++) {
                const float v = acc[i][j][r];
                const float vp = __shfl_xor(v, 1);
                const float g = (lm & 1) ? vp : v;
                const float u = (lm & 1) ? v : vp;
                const float h = g / (1.f + __expf(-g)) * u;
                if (!(lm & 1)) {
                    const int row = row0 + wm + i * 16 + lq * 4 + r;
                    const int col = col0 + wn + j * 16 + lm;    // even
                    Hp[(size_t)row * HID_ + (col >> 1)] = f2bf(h);
                }
            }
}

// ---------------------------------------------------------------------------
// Routed MoE down GEMM, split-K: out[tok[r]] += wt[r] * (Hc[e] @ wd[e]^T).
// grid (8, 16, E*2): z -> (expert, k-slice of HID/2).
// ---------------------------------------------------------------------------
__global__ __launch_bounds__(256) void down_idx_kernel(
    const ushort_t* __restrict__ Hc, const ushort_t* __restrict__ Wd,
    const int* __restrict__ cnt, const int* __restrict__ tok,
    const float* __restrict__ wt, float* __restrict__ out)
{
    const int e = blockIdx.z >> 1;
    const int ks = blockIdx.z & 1;
    const int cntE = cnt[e];
    const int row0 = blockIdx.y * 128;
    if (row0 >= cntE) return;
    const int col0 = blockIdx.x * 128;
    const int kBegin = ks * (HID_ / 2);
    const ushort_t* A = Hc + (size_t)e * T_ * HID_;
    const ushort_t* Bt = Wd + (size_t)e * D_ * HID_;

    __shared__ __align__(16) ushort_t As[128 * 32];
    __shared__ __align__(16) ushort_t Bs[128 * 32];
    const int tid = threadIdx.x, w = tid >> 6, lane = tid & 63;
    const int lr = lane >> 2, lc = (lane & 3) * 8;
    const int wm = (w >> 1) * 64, wn = (w & 1) * 64;
    const int lm = lane & 15, lq = lane >> 4;

    floatx4 acc[4][4] = {};

    const ushort_t* Ap = A + (size_t)(row0 + w * 16 + lr) * HID_ + kBegin + lc;
    const ushort_t* Bp = Bt + (size_t)(col0 + w * 16 + lr) * HID_ + kBegin + lc;
    ushort_t* lA = As + w * 512;
    ushort_t* lB = Bs + w * 512;

    for (int k0 = 0; k0 < HID_ / 2; k0 += 32) {
        __syncthreads();
        gl2lds16(Ap + k0, lA);
        gl2lds16(Ap + k0 + (size_t)64 * HID_, lA + 2048);
        gl2lds16(Bp + k0, lB);
        gl2lds16(Bp + k0 + (size_t)64 * HID_, lB + 2048);
        __syncthreads();
        bf16x8 a[4], b[4];
#pragma unroll
        for (int i = 0; i < 4; i++)
            a[i] = *(const bf16x8*)(As + (wm + i * 16 + lm) * 32 + lq * 8);
#pragma unroll
        for (int j = 0; j < 4; j++)
            b[j] = *(const bf16x8*)(Bs + (wn + j * 16 + lm) * 32 + lq * 8);
#pragma unroll
        for (int i = 0; i < 4; i++)
#pragma unroll
            for (int j = 0; j < 4; j++)
                acc[i][j] = __builtin_amdgcn_mfma_f32_16x16x32_bf16(a[i], b[j], acc[i][j], 0, 0, 0);
    }

#pragma unroll
    for (int i = 0; i < 4; i++)
#pragma unroll
        for (int r = 0; r < 4; r++) {
            const int row = row0 + wm + i * 16 + lq * 4 + r;
            if (row < cntE) {
                const int t = tok[e * T_ + row];
                const float scale = wt[e * T_ + row];
#pragma unroll
                for (int j = 0; j < 4; j++) {
                    const int col = col0 + wn + j * 16 + lm;
                    atomicAdd(&out[(size_t)t * D_ + col], scale * acc[i][j][r]);
                }
            }
        }
}

// ---------------------------------------------------------------------------
// RoPE cos/sin tables (np f32 semantics via f64 pow/cos/sin)
// ---------------------------------------------------------------------------
__global__ __launch_bounds__(256) void rope_table_kernel(
    float* __restrict__ ctab, float* __restrict__ stab)
{
    const int i = blockIdx.x * 256 + threadIdx.x;   // S_*32
    if (i >= S_ * 32) return;
    const int s = i >> 5, p = i & 31;
    const double e = (double)(2 * p) / 64.0;
    const float pf = (float)pow(10000.0, e);
    const float invf = 1.0f / pf;
    const float fr = (float)s * invf;
    ctab[i] = (float)cos((double)fr);
    stab[i] = (float)sin((double)fr);
}

// ---------------------------------------------------------------------------
// Fused flash attention — two-word bf16 MFMA, online softmax, single pass.
// Grid (bh=64, qt=16), 256 thr = 4 waves; wave w owns kv/d chunk w*16..+15.
// Per kv-chunk (64 keys): stage K -> QK MFMA -> cross-wave rowmax ->
// overwrite K LDS with V^T (regs prefetched under QK) -> p=exp(s-m'),
// rescale running (m,l,O) -> PV MFMA accumulate. Emits O/l directly as
// hi/lo bf16 planes (no Opart/Ml/combine pass).
// Online rescaling is algebraically identical to the old chunk-max+combine
// (f32 m/l, f32 p summed pre-split) -> routing-safe.
// ---------------------------------------------------------------------------
__global__ __launch_bounds__(256, 4) void attn_fused_kernel(
    const float* __restrict__ qkv, ushort_t* __restrict__ aoh,
    ushort_t* __restrict__ aol)
{
    const int bh = blockIdx.x;                 // b*16+h
    const int qt = blockIdx.y;
    const int b = bh >> 4, h = bh & 15;
    const int q0 = qt * 32;
    const int nchunk = (qt >> 1) + 1;

    // bf16 hi/lo tiles, row stride 72 (pad 8) keeps b128 reads 16B-aligned
    __shared__ __align__(16) ushort_t qsh[32 * 72], qsl[32 * 72];  // Q rows (q, d)
    __shared__ __align__(16) ushort_t kvh[64 * 72], kvl[64 * 72];  // K rows, then V^T rows
    __shared__ __align__(16) ushort_t psh[32 * 72], psl[32 * 72];  // P rows (q, kv)
    __shared__ __align__(16) float redm[32][4];      // per-wave row max
    __shared__ __align__(16) float redl[32][4];      // per-wave row sum

    const int tid = threadIdx.x, w = tid >> 6, lane = tid & 63;
    const int lm = lane & 15, lq = lane >> 4;

    // ---- stage Q once (32x64 f32 -> hi/lo bf16); 8 elements per thread
    {
        const int row = tid >> 3, g = tid & 7;
        const float* src = qkv + (size_t)(b * S_ + q0 + row) * D3_ + h * HD_ + g * 8;
        const float4 v0 = *(const float4*)(src);
        const float4 v1 = *(const float4*)(src + 4);
        ushort4 h0, l0, h1, l1;
        split2(v0.x, h0.x, l0.x); split2(v0.y, h0.y, l0.y);
        split2(v0.z, h0.z, l0.z); split2(v0.w, h0.w, l0.w);
        split2(v1.x, h1.x, l1.x); split2(v1.y, h1.y, l1.y);
        split2(v1.z, h1.z, l1.z); split2(v1.w, h1.w, l1.w);
        *(ushort4*)(qsh + row * 72 + g * 8)     = h0;
        *(ushort4*)(qsh + row * 72 + g * 8 + 4) = h1;
        *(ushort4*)(qsl + row * 72 + g * 8)     = l0;
        *(ushort4*)(qsl + row * 72 + g * 8 + 4) = l1;
    }

    // running state: rows q = i*16 + lq*4 + r, col d = w*16 + lm
    float mrun[2][4], lrun[2][4];
    floatx4 oacc[2] = {};
#pragma unroll
    for (int i = 0; i < 2; i++)
#pragma unroll
        for (int r = 0; r < 4; r++) { mrun[i][r] = -INFINITY; lrun[i][r] = 0.f; }

    for (int c = 0; c < nchunk; c++) {
        const int c0 = c * 64;

        // ---- stage K chunk (64x64 f32 -> hi/lo bf16) into the shared K/V buf
#pragma unroll
        for (int it = 0; it < 2; it++) {
            const int i = tid + it * 256;
            const int row = i >> 3, g = i & 7;
            const float* src = qkv + (size_t)(b * S_ + c0 + row) * D3_ + D_ + h * HD_ + g * 8;
            const float4 v0 = *(const float4*)(src);
            const float4 v1 = *(const float4*)(src + 4);
            ushort4 h0, l0, h1, l1;
            split2(v0.x, h0.x, l0.x); split2(v0.y, h0.y, l0.y);
            split2(v0.z, h0.z, l0.z); split2(v0.w, h0.w, l0.w);
            split2(v1.x, h1.x, l1.x); split2(v1.y, h1.y, l1.y);
            split2(v1.z, h1.z, l1.z); split2(v1.w, h1.w, l1.w);
            *(ushort4*)(kvh + row * 72 + g * 8)     = h0;
            *(ushort4*)(kvh + row * 72 + g * 8 + 4) = h1;
            *(ushort4*)(kvl + row * 72 + g * 8)     = l0;
            *(ushort4*)(kvl + row * 72 + g * 8 + 4) = l1;
        }
        // ---- prefetch V (f32) into registers; latency hides under QK
        float4 vreg[4];
#pragma unroll
        for (int it = 0; it < 4; it++) {
            const int i = tid + it * 256;
            const int k = i >> 4, g = i & 15;
            vreg[it] = *(const float4*)(qkv + (size_t)(b * S_ + c0 + k) * D3_ + 2 * D_ + h * HD_ + g * 4);
        }
        __syncthreads();   // K (and Q on first iter) visible

        // ---- scores: wave w -> S[32 q][16 kv] chunk; 3 MFMAs per product
        floatx4 acc[2] = {};
#pragma unroll
        for (int k0 = 0; k0 < 64; k0 += 32) {
            const bf16x8 bh16 = *(const bf16x8*)(kvh + (w * 16 + lm) * 72 + k0 + lq * 8);
            const bf16x8 bl16 = *(const bf16x8*)(kvl + (w * 16 + lm) * 72 + k0 + lq * 8);
#pragma unroll
            for (int i = 0; i < 2; i++) {
                const bf16x8 ah = *(const bf16x8*)(qsh + (i * 16 + lm) * 72 + k0 + lq * 8);
                const bf16x8 al = *(const bf16x8*)(qsl + (i * 16 + lm) * 72 + k0 + lq * 8);
                acc[i] = __builtin_amdgcn_mfma_f32_16x16x32_bf16(ah, bh16, acc[i], 0, 0, 0);
                acc[i] = __builtin_amdgcn_mfma_f32_16x16x32_bf16(al, bh16, acc[i], 0, 0, 0);
                acc[i] = __builtin_amdgcn_mfma_f32_16x16x32_bf16(ah, bl16, acc[i], 0, 0, 0);
            }
        }

        // ---- mask + scale, per-row max over this wave's 16 kv
        float sv[2][4];
        const int kvg = c0 + w * 16 + lm;
#pragma unroll
        for (int i = 0; i < 2; i++)
#pragma unroll
            for (int r = 0; r < 4; r++) {
                const int qg = q0 + i * 16 + lq * 4 + r;
                float v = (kvg <= qg) ? acc[i][r] * 0.125f : -INFINITY;
                sv[i][r] = v;
#pragma unroll
                for (int off = 1; off < 16; off <<= 1) v = fmaxf(v, __shfl_xor(v, off));
                if (lm == 0) redm[i * 16 + lq * 4 + r][w] = v;
            }
        __syncthreads();   // redm complete; all K reads done

        // ---- stage V transposed into the shared buffer (overwrites K)
#pragma unroll
        for (int it = 0; it < 4; it++) {
            const int i = tid + it * 256;
            const int k = i >> 4, g = i & 15;
            const float4 v = vreg[it];
            ushort_t hh, ll;
            split2(v.x, hh, ll); kvh[(g * 4 + 0) * 72 + k] = hh; kvl[(g * 4 + 0) * 72 + k] = ll;
            split2(v.y, hh, ll); kvh[(g * 4 + 1) * 72 + k] = hh; kvl[(g * 4 + 1) * 72 + k] = ll;
            split2(v.z, hh, ll); kvh[(g * 4 + 2) * 72 + k] = hh; kvl[(g * 4 + 2) * 72 + k] = ll;
            split2(v.w, hh, ll); kvh[(g * 4 + 3) * 72 + k] = hh; kvl[(g * 4 + 3) * 72 + k] = ll;
        }

        // ---- online softmax: new row max, p = exp(s - m'), rescale factor
        float sclr[2][4];
#pragma unroll
        for (int i = 0; i < 2; i++)
#pragma unroll
            for (int r = 0; r < 4; r++) {
                const int q = i * 16 + lq * 4 + r;
                const float4 m4 = *(const float4*)&redm[q][0];
                const float Mc = fmaxf(fmaxf(m4.x, m4.y), fmaxf(m4.z, m4.w));
                const float Mn = fmaxf(mrun[i][r], Mc);
                const float p = expf(sv[i][r] - Mn);
                ushort_t ph, pl;
                split2(p, ph, pl);
                psh[q * 72 + w * 16 + lm] = ph;
                psl[q * 72 + w * 16 + lm] = pl;
                float sum = p;
#pragma unroll
                for (int off = 1; off < 16; off <<= 1) sum += __shfl_xor(sum, off);
                if (lm == 0) redl[q][w] = sum;
                sclr[i][r] = expf(mrun[i][r] - Mn);   // 0 on first chunk
                mrun[i][r] = Mn;
            }
        __syncthreads();   // ps, V^T, redl ready

        // ---- update l, rescale O
#pragma unroll
        for (int i = 0; i < 2; i++)
#pragma unroll
            for (int r = 0; r < 4; r++) {
                const int q = i * 16 + lq * 4 + r;
                const float4 l4 = *(const float4*)&redl[q][0];
                const float lc = l4.x + l4.y + l4.z + l4.w;
                lrun[i][r] = lrun[i][r] * sclr[i][r] + lc;
                oacc[i][r] *= sclr[i][r];
            }

        // ---- PV: O[32 q][16 d chunk w] += (Ph+Pl) · (Vh+Vl)^T
#pragma unroll
        for (int k0 = 0; k0 < 64; k0 += 32) {
            const bf16x8 bh16 = *(const bf16x8*)(kvh + (w * 16 + lm) * 72 + k0 + lq * 8);
            const bf16x8 bl16 = *(const bf16x8*)(kvl + (w * 16 + lm) * 72 + k0 + lq * 8);
#pragma unroll
            for (int i = 0; i < 2; i++) {
                const bf16x8 ah = *(const bf16x8*)(psh + (i * 16 + lm) * 72 + k0 + lq * 8);
                const bf16x8 al = *(const bf16x8*)(psl + (i * 16 + lm) * 72 + k0 + lq * 8);
                oacc[i] = __builtin_amdgcn_mfma_f32_16x16x32_bf16(ah, bh16, oacc[i], 0, 0, 0);
                oacc[i] = __builtin_amdgcn_mfma_f32_16x16x32_bf16(al, bh16, oacc[i], 0, 0, 0);
                oacc[i] = __builtin_amdgcn_mfma_f32_16x16x32_bf16(ah, bl16, oacc[i], 0, 0, 0);
            }
        }
        __syncthreads();   // PV reads done before next chunk overwrites kv/ps
    }

    // ---- epilogue: normalize and emit hi/lo bf16 planes
    const int col = h * HD_ + w * 16 + lm;
#pragma unroll
    for (int i = 0; i < 2; i++)
#pragma unroll
        for (int r = 0; r < 4; r++) {
            const int q = i * 16 + lq * 4 + r;
            const int t = b * S_ + q0 + q;
            const float v = oacc[i][r] / lrun[i][r];
            ushort_t hh, ll;
            split2(v, hh, ll);
            aoh[(size_t)t * D_ + col] = hh;
            aol[(size_t)t * D_ + col] = ll;
        }
}

// ---------------------------------------------------------------------------
// Gating + routing. bf16-rounded logits, top-2 lowest-index tie-break.
// ---------------------------------------------------------------------------
__global__ __launch_bounds__(64) void gate_kernel(
    const ushort_t* __restrict__ xn2, const float* __restrict__ gate_w,
    int* __restrict__ cnt, int* __restrict__ tok, float* __restrict__ wt,
    float* __restrict__ probs)
{
    const int t = blockIdx.x;
    const int lane = threadIdx.x;
    float acc[8] = {0, 0, 0, 0, 0, 0, 0, 0};
    for (int d = lane; d < D_; d += 64) {
        const float xv = bf2f(xn2[(size_t)t * D_ + d]);
        const float4 g0 = ((const float4*)(gate_w + d * 8))[0];
        const float4 g1 = ((const float4*)(gate_w + d * 8))[1];
        acc[0] = fmaf(xv, bf2f(f2bf(g0.x)), acc[0]);
        acc[1] = fmaf(xv, bf2f(f2bf(g0.y)), acc[1]);
        acc[2] = fmaf(xv, bf2f(f2bf(g0.z)), acc[2]);
        acc[3] = fmaf(xv, bf2f(f2bf(g0.w)), acc[3]);
        acc[4] = fmaf(xv, bf2f(f2bf(g1.x)), acc[4]);
        acc[5] = fmaf(xv, bf2f(f2bf(g1.y)), acc[5]);
        acc[6] = fmaf(xv, bf2f(f2bf(g1.z)), acc[6]);
        acc[7] = fmaf(xv, bf2f(f2bf(g1.w)), acc[7]);
    }
#pragma unroll
    for (int e = 0; e < 8; e++) {
#pragma unroll
        for (int off = 32; off; off >>= 1) acc[e] += __shfl_xor(acc[e], off);
        acc[e] = bf2f(f2bf(acc[e]));   // bf16 result of the bf16 matmul
    }

    if (lane == 0) {
        int i1 = 0;
        for (int e = 1; e < 8; e++) if (acc[e] > acc[i1]) i1 = e;
        int i2 = (i1 == 0) ? 1 : 0;
        for (int e = 0; e < 8; e++) if (e != i1 && acc[e] > acc[i2]) i2 = e;
        const float e2 = expf(acc[i2] - acc[i1]);
        const float w1 = 1.f / (1.f + e2);
        const float w2 = e2 * w1;
        const int p1 = atomicAdd(&cnt[i1], 1);
        tok[i1 * T_ + p1] = t; wt[i1 * T_ + p1] = w1;
        const int p2 = atomicAdd(&cnt[i2], 1);
        tok[i2 * T_ + p2] = t; wt[i2 * T_ + p2] = w2;
        const float mx = acc[i1];
        float se = 0.f, pe[8];
        for (int e = 0; e < 8; e++) { pe[e] = expf(acc[e] - mx); se += pe[e]; }
        const float inv = 1.f / se;
        for (int e = 0; e < 8; e++) probs[t * 8 + e] = pe[e] * inv;
    }
}

__global__ void zero_route_kernel(int* __restrict__ cnt)
{
    if (threadIdx.x < 8) cnt[threadIdx.x] = 0;
}

// ---------------------------------------------------------------------------
// dist = probs.mean(0); lb = E * sum(dist^2); writes out tail.
// ---------------------------------------------------------------------------
__global__ __launch_bounds__(256) void reduce_dist_kernel(
    const float* __restrict__ probs, float* __restrict__ out)
{
    __shared__ float part[256];
    __shared__ float dist8[8];
    const int tid = threadIdx.x;
    const int e = tid & 7, chunk = tid >> 3;   // 32 chunks
    float s = 0.f;
    for (int t = chunk; t < T_; t += 32) s += probs[t * 8 + e];
    part[tid] = s;
    __syncthreads();
    if (tid < 8) {
        float tot = 0.f;
        for (int c = 0; c < 32; c++) tot += part[c * 8 + tid];
        const float dv = tot * (1.0f / T_);
        dist8[tid] = dv;
        out[(size_t)T_ * D_ + 1 + tid] = dv;
    }
    __syncthreads();
    if (tid == 0) {
        float s2 = 0.f;
        for (int k = 0; k < 8; k++) s2 += dist8[k] * dist8[k];
        out[(size_t)T_ * D_] = (float)E_ * s2;
    }
}

// ---------------------------------------------------------------------------
// Launch
// ---------------------------------------------------------------------------
extern "C" void kernel_launch(void* const* d_in, const int* in_sizes, int n_in,
                              void* d_out, int out_size, void* d_ws, size_t ws_size,
                              hipStream_t stream)
{
    const float* x      = (const float*)d_in[0];
    const float* ln1_g  = (const float*)d_in[1];
    const float* ln1_b  = (const float*)d_in[2];
    const float* ln2_g  = (const float*)d_in[3];
    const float* ln2_b  = (const float*)d_in[4];
    const float* w_qkv  = (const float*)d_in[5];
    const float* w_o    = (const float*)d_in[6];
    const float* gate_w = (const float*)d_in[7];
    const float* w_gate = (const float*)d_in[8];
    const float* w_up   = (const float*)d_in[9];
    const float* w_down = (const float*)d_in[10];
    float* out = (float*)d_out;

    char* ws = (char*)d_ws;
    size_t off = 0;
    auto alloc = [&](size_t bytes) { size_t o = off; off += (bytes + 255) & ~(size_t)255; return o; };
    // persistent-through-MoE region
    ushort_t* wguT  = (ushort_t*)(ws + alloc((size_t)E_ * GU_ * D_ * 2));   // 58.7 MB
    ushort_t* wdT   = (ushort_t*)(ws + alloc((size_t)E_ * D_ * HID_ * 2));  // 29.4 MB
    ushort_t* xnh   = (ushort_t*)(ws + alloc((size_t)T_ * D_ * 4));         // hi+lo planes
    ushort_t* xnl   = xnh + (size_t)T_ * D_;
    ushort_t* xn2   = (ushort_t*)(ws + alloc((size_t)T_ * D_ * 2));
    int*      cnt   = (int*)     (ws + alloc(64));
    int*      tok   = (int*)     (ws + alloc((size_t)E_ * T_ * 4));
    float*    wt    = (float*)   (ws + alloc((size_t)E_ * T_ * 4));
    float*    probs = (float*)   (ws + alloc((size_t)T_ * E_ * 4));
    float*    ctab  = (float*)   (ws + alloc((size_t)S_ * 32 * 4));
    float*    stab  = (float*)   (ws + alloc((size_t)S_ * 32 * 4));
    // scratch union (aliased by lifetime):
    //   phase A: qkvP0 [0,25.2) + wqkvT hi/lo [25.2,37.8)   (QKV MFMA GEMM)
    //   phase B: qkv=P0 [0,25.2) read by fused attn; aoh/aol [25.2,33.6) written
    //   phase C: x1 [8,16) + woT hi/lo [16,24) + aoh/aol live
    //   phase D: Hc [0,58.7)
    const size_t qkvBytes = (size_t)T_ * D3_ * 4;
    const size_t scratch0 = alloc(qkvBytes + ((size_t)40 << 20));
    float*    qkvP0 = (float*)   (ws + scratch0);
    ushort_t* wqkvTh= (ushort_t*)(ws + scratch0 + qkvBytes);          // dead after QKV GEMM
    ushort_t* wqkvTl= wqkvTh + (size_t)D3_ * D_;
    ushort_t* aoh   = (ushort_t*)(ws + scratch0 + qkvBytes);          // alias wqkvT (dead)
    ushort_t* aol   = aoh + (size_t)T_ * D_;
    float*    x1    = (float*)   (ws + scratch0 + (size_t)T_ * D_ * 4);          // post-attn
    ushort_t* woTh  = (ushort_t*)(ws + scratch0 + (size_t)T_ * D_ * 8);          // post-attn
    ushort_t* woTl  = woTh + (size_t)D_ * D_;
    ushort_t* Hc    = (ushort_t*)(ws + scratch0);                     // alias all (MoE phase)
    (void)ws_size; (void)in_sizes; (void)n_in; (void)out_size;

    // weight transposes -> bf16 (N x K); gate/up interleaved into wguT
    hipLaunchKernelGGL(transpose_bf16_kernel, dim3(HID_ / 32, D_ / 32, E_), dim3(256), 0, stream,
                       w_gate, wguT, D_, HID_, 2, 0, (long)GU_ * D_);
    hipLaunchKernelGGL(transpose_bf16_kernel, dim3(HID_ / 32, D_ / 32, E_), dim3(256), 0, stream,
                       w_up, wguT, D_, HID_, 2, 1, (long)GU_ * D_);
    hipLaunchKernelGGL(transpose_bf16_kernel, dim3(D_ / 32, HID_ / 32, E_), dim3(256), 0, stream,
                       w_down, wdT, HID_, D_, 1, 0, (long)D_ * HID_);

    // w_qkv (D x 3D) -> hi/lo bf16 planes (3D x D)
    hipLaunchKernelGGL(transpose_split_kernel, dim3(D3_ / 32, D_ / 32), dim3(256), 0, stream,
                       w_qkv, wqkvTh, wqkvTl, D_, D3_);

    // RoPE tables
    hipLaunchKernelGGL(rope_table_kernel, dim3((S_ * 32 + 255) / 256), dim3(256), 0, stream,
                       ctab, stab);

    // LN1 -> hi/lo bf16 planes
    hipLaunchKernelGGL(ln_kernel, dim3(T_), dim3(256), 0, stream,
                       x, ln1_g, ln1_b, (ushort_t*)nullptr, xnh, xnl);

    // QKV two-word bf16 MFMA GEMM: grid (24,16) -> f32 qkv
    hipLaunchKernelGGL(gemm2w_kernel, dim3(D3_ / 128, T_ / 128), dim3(256), 0, stream,
                       xnh, xnl, wqkvTh, wqkvTl, (const float*)nullptr, qkvP0,
                       (float*)nullptr, D3_);

    // RoPE rotate q/k in place
    hipLaunchKernelGGL(rope_kernel, dim3(4, T_), dim3(256), 0, stream,
                       qkvP0, ctab, stab);

    // fused flash attention -> attn output hi/lo planes (wqkvT dead now)
    hipLaunchKernelGGL(attn_fused_kernel, dim3(64, 16), dim3(256), 0, stream,
                       qkvP0, aoh, aol);

    // w_o (D x D) -> hi/lo bf16 planes (D x D); qkvP0 dead now
    hipLaunchKernelGGL(transpose_split_kernel, dim3(D_ / 32, D_ / 32), dim3(256), 0, stream,
                       w_o, woTh, woTl, D_, D_);

    // W_O two-word bf16 MFMA GEMM + residual -> x1 AND out
    hipLaunchKernelGGL(gemm2w_kernel, dim3(D_ / 128, T_ / 128), dim3(256), 0, stream,
                       aoh, aol, woTh, woTl, x, x1, out, D_);

    // LN2 (bf16)
    hipLaunchKernelGGL(ln_kernel, dim3(T_), dim3(256), 0, stream,
                       x1, ln2_g, ln2_b, xn2, (ushort_t*)nullptr, (ushort_t*)nullptr);

    // gating + routing + aux outputs
    hipLaunchKernelGGL(zero_route_kernel, dim3(1), dim3(64), 0, stream, cnt);
    hipLaunchKernelGGL(gate_kernel, dim3(T_), dim3(64), 0, stream,
                       xn2, gate_w, cnt, tok, wt, probs);
    hipLaunchKernelGGL(reduce_dist_kernel, dim3(1), dim3(256), 0, stream, probs, out);

    // MoE routed: fused gate+up (+silu), then weighted down (split-K=2)
    hipLaunchKernelGGL(gateup_idx_kernel, dim3(GU_ / 128, T_ / 128, E_), dim3(256), 0, stream,
                       xn2, wguT, cnt, tok, Hc);
    hipLaunchKernelGGL(down_idx_kernel, dim3(D_ / 128, T_ / 128, E_ * 2), dim3(256), 0, stream,
                       Hc, wdT, cnt, tok, wt, out);
}